// Round 3
// baseline (7990.909 us; speedup 1.0000x reference)
//
#include <hip/hip_runtime.h>
#include <hip/hip_bf16.h>
#include <cstdint>
#include <cstddef>

#define L_SEQ   8192
#define DMODEL  768
#define NHEADS  24
#define DINNER  1536
#define NPROJ   3096      /* 24 * 129 */
#define NTOK    16384
#define SEG_T   2048      /* tokens per segment */
#define NSEG    8
#define SEG_CH  32        /* chunks per segment */
#define RMS_EPS 1.1920929e-07f

typedef __hip_bfloat16 bf16;

__device__ __forceinline__ float clampf(float x, float lo, float hi) {
    return fminf(fmaxf(x, lo), hi);
}
__device__ __forceinline__ float bf2f(bf16 v) { return __bfloat162float(v); }
__device__ __forceinline__ bf16  f2bf(float v) { return __float2bfloat16(v); }

__device__ __forceinline__ float4 ld4f(const float* p) { return *(const float4*)p; }
__device__ __forceinline__ float4 ld4f(const bf16* p) {
    uint2 v = *(const uint2*)(const void*)p;
    float4 r;
    r.x = __uint_as_float(v.x << 16);
    r.y = __uint_as_float(v.x & 0xffff0000u);
    r.z = __uint_as_float(v.y << 16);
    r.w = __uint_as_float(v.y & 0xffff0000u);
    return r;
}
__device__ __forceinline__ void st1(float* p, float v) { *p = v; }
__device__ __forceinline__ void st1(bf16* p, float v) { *p = f2bf(v); }
__device__ __forceinline__ void st4(float* p, float4 v) { *(float4*)p = v; }
__device__ __forceinline__ void st4(bf16* p, float4 v) {
    p[0] = f2bf(v.x); p[1] = f2bf(v.y); p[2] = f2bf(v.z); p[3] = f2bf(v.w);
}

// ---------------------------------------------------------------- RMSNorm (segment: T rows)
__global__ __launch_bounds__(256) void k_rmsnorm(const float* __restrict__ hs,
                                                 const float* __restrict__ w,
                                                 float* __restrict__ xn) {
    int t = blockIdx.x;
    const float* p = hs + (size_t)t * DMODEL;
    float s = 0.f;
    for (int i = threadIdx.x; i < DMODEL; i += 256) { float v = p[i]; s += v * v; }
    for (int off = 32; off; off >>= 1) s += __shfl_xor(s, off, 64);
    __shared__ float ws4[4];
    int lane = threadIdx.x & 63, wv = threadIdx.x >> 6;
    if (lane == 0) ws4[wv] = s;
    __syncthreads();
    s = ws4[0] + ws4[1] + ws4[2] + ws4[3];
    float r = 1.0f / sqrtf(s * (1.0f / DMODEL) + RMS_EPS);
    float* o = xn + (size_t)t * DMODEL;
    for (int i = threadIdx.x; i < DMODEL; i += 256) o[i] = p[i] * r * w[i];
}

// ---------------------------------------------------------------- GEMM  C[M,N] = A[M,K] @ B[N,K]^T + bias
template <typename TA, typename TC, int EPI>
__global__ __launch_bounds__(256) void k_gemm(const TA* __restrict__ A,
                                              const float* __restrict__ B,
                                              const float* __restrict__ bias,
                                              TC* __restrict__ C,
                                              int M, int N, int K,
                                              const float* __restrict__ resid,
                                              const float* __restrict__ gatep) {
    __shared__ float As[16][68];
    __shared__ float Bs[16][68];
    int tid = threadIdx.x;
    int m0 = blockIdx.y * 64, n0 = blockIdx.x * 64;
    int tm = (tid >> 4) << 2, tn = (tid & 15) << 2;
    int lr = tid >> 2, lk = (tid & 3) << 2;
    const TA* Ap = A + (size_t)(m0 + lr) * K + lk;
    int nrow = n0 + lr;
    bool bok = nrow < N;
    const float* Bp = B + (size_t)nrow * K + lk;
    float acc[4][4] = {};
    for (int k0 = 0; k0 < K; k0 += 16) {
        float4 a4 = ld4f(Ap + k0);
        float4 b4 = bok ? *(const float4*)(Bp + k0) : make_float4(0.f, 0.f, 0.f, 0.f);
        __syncthreads();
        As[lk + 0][lr] = a4.x; As[lk + 1][lr] = a4.y; As[lk + 2][lr] = a4.z; As[lk + 3][lr] = a4.w;
        Bs[lk + 0][lr] = b4.x; Bs[lk + 1][lr] = b4.y; Bs[lk + 2][lr] = b4.z; Bs[lk + 3][lr] = b4.w;
        __syncthreads();
#pragma unroll
        for (int kk = 0; kk < 16; ++kk) {
            const float4 a_ = *(const float4*)&As[kk][tm];
            const float4 b_ = *(const float4*)&Bs[kk][tn];
            const float ar[4] = {a_.x, a_.y, a_.z, a_.w};
            const float br[4] = {b_.x, b_.y, b_.z, b_.w};
#pragma unroll
            for (int r = 0; r < 4; ++r)
#pragma unroll
                for (int q = 0; q < 4; ++q) acc[r][q] += ar[r] * br[q];
        }
    }
    float gate = (EPI == 1) ? *gatep : 0.f;
    if (n0 + 64 <= N) {
#pragma unroll
        for (int r = 0; r < 4; ++r) {
            int gm = m0 + tm + r, gn = n0 + tn;
            float4 v;
            v.x = acc[r][0] + bias[gn + 0];
            v.y = acc[r][1] + bias[gn + 1];
            v.z = acc[r][2] + bias[gn + 2];
            v.w = acc[r][3] + bias[gn + 3];
            if (EPI == 1) {
                const float4 rs = *(const float4*)&resid[(size_t)gm * N + gn];
                v.x = rs.x + clampf(v.x, -100.f, 100.f) * gate;
                v.y = rs.y + clampf(v.y, -100.f, 100.f) * gate;
                v.z = rs.z + clampf(v.z, -100.f, 100.f) * gate;
                v.w = rs.w + clampf(v.w, -100.f, 100.f) * gate;
            }
            st4(&C[(size_t)gm * N + gn], v);
        }
    } else {
#pragma unroll
        for (int r = 0; r < 4; ++r) {
            int gm = m0 + tm + r;
#pragma unroll
            for (int q = 0; q < 4; ++q) {
                int gn = n0 + tn + q;
                if (gn < N) {
                    float v = acc[r][q] + bias[gn];
                    if (EPI == 1)
                        v = resid[(size_t)gm * N + gn] + clampf(v, -100.f, 100.f) * gate;
                    st1(&C[(size_t)gm * N + gn], v);
                }
            }
        }
    }
}

// ---------------------------------------------------------------- save last 3 rows of x for next segment's conv halo
__global__ __launch_bounds__(256) void k_save_halo(const bf16* __restrict__ x,
                                                   bf16* __restrict__ dst) {
    int i = blockIdx.x * 256 + threadIdx.x;
    if (i < 3 * DINNER) dst[i] = x[(size_t)(SEG_T - 3) * DINNER + i];
}

// ---------------------------------------------------------------- depthwise causal conv (k=4) + SiLU, segment-local
__global__ __launch_bounds__(256) void k_conv_silu(const bf16* __restrict__ x,
                                                   const bf16* __restrict__ xh,
                                                   const float* __restrict__ cw,
                                                   const float* __restrict__ cb,
                                                   bf16* __restrict__ xc,
                                                   int l0) {
    int c = blockIdx.x * 256 + threadIdx.x;   // < DINNER
    int r = blockIdx.y;                       // 0..SEG_T-1
    int l = l0 + r;
    float acc = cb[c];
#pragma unroll
    for (int k = 0; k < 4; ++k) {
        int lp = l - 3 + k;
        if (lp < 0) continue;
        float v = (lp < l0) ? bf2f(xh[(size_t)(lp - l0 + 3) * DINNER + c])
                            : bf2f(x[(size_t)(lp - l0) * DINNER + c]);
        acc += cw[c * 4 + k] * v;
    }
    float sig = 1.f / (1.f + expf(-acc));
    xc[(size_t)r * DINNER + c] = f2bf(acc * sig);
}

// ---------------------------------------------------------------- per-(t,h): A value, 1/||B||, 1/||C|| (segment-local)
__global__ __launch_bounds__(256) void k_prep(const bf16* __restrict__ xp,
                                              const float* __restrict__ A_log,
                                              float* __restrict__ Aarr,
                                              float* __restrict__ invB,
                                              float* __restrict__ invC) {
    int wv = threadIdx.x >> 6, lane = threadIdx.x & 63;
    int idx = blockIdx.x * 4 + wv;            // t_local*24 + h, < SEG_T*24
    int t = idx / 24, h = idx - t * 24;
    const bf16* base = xp + (size_t)t * NPROJ + h * 129;
    float b = bf2f(base[1 + lane]), c = bf2f(base[65 + lane]);
    float sb = b * b, sc = c * c;
    for (int off = 32; off; off >>= 1) {
        sb += __shfl_xor(sb, off, 64);
        sc += __shfl_xor(sc, off, 64);
    }
    if (lane == 0) {
        invB[idx] = 1.f / fmaxf(sqrtf(sb), 1e-12f);
        invC[idx] = 1.f / fmaxf(sqrtf(sc), 1e-12f);
        float dt = clampf(bf2f(base[0]), -10.f, 10.f);
        float dts = clampf(log1pf(expf(dt)), 0.01f, 10.f);
        float A = clampf(A_log[h], -2.3f, -0.01f) * dts;
        Aarr[idx] = clampf(A, -20.f, -0.001f);
    }
}

// ---------------------------------------------------------------- chunk surprise (segment-local inputs, global cs)
__global__ __launch_bounds__(256) void k_surprise(const bf16* __restrict__ xp,
                                                  const bf16* __restrict__ xc,
                                                  const float* __restrict__ invB,
                                                  float* __restrict__ cs,
                                                  int b, int l0) {
    int g = blockIdx.x;                // 0..767
    int h = g >> 5, nl = g & 31;
    int t0l = nl * 64;
    __shared__ float Bs[64][68];
    __shared__ float Xs[64][68];
    int tid = threadIdx.x, s = tid & 63, cw0 = tid >> 6;
    for (int it = 0; it < 16; ++it) {
        int c = cw0 + (it << 2);
        int t = t0l + c;
        Bs[c][s] = bf2f(xp[(size_t)t * NPROJ + h * 129 + 1 + s]) * invB[t * 24 + h];
        Xs[c][s] = bf2f(xc[(size_t)t * DINNER + h * 64 + s]);
    }
    __syncthreads();
    int s0 = (tid >> 4) << 2, d0 = (tid & 15) << 2;
    float acc[4][4] = {};
    for (int c = 0; c < 64; ++c) {
        const float4 b_ = *(const float4*)&Bs[c][s0];
        const float4 x_ = *(const float4*)&Xs[c][d0];
        const float br[4] = {b_.x, b_.y, b_.z, b_.w};
        const float xr[4] = {x_.x, x_.y, x_.z, x_.w};
#pragma unroll
        for (int r = 0; r < 4; ++r)
#pragma unroll
            for (int q = 0; q < 4; ++q) acc[r][q] += br[r] * xr[q];
    }
    float ss = 0.f;
#pragma unroll
    for (int r = 0; r < 4; ++r)
#pragma unroll
        for (int q = 0; q < 4; ++q) ss += acc[r][q] * acc[r][q];
    for (int off = 32; off; off >>= 1) ss += __shfl_xor(ss, off, 64);
    __shared__ float ws4[4];
    int lane = tid & 63, wv = tid >> 6;
    if (lane == 0) ws4[wv] = ss;
    __syncthreads();
    if (tid == 0)
        cs[(size_t)(b * 24 + h) * 128 + (l0 >> 6) + nl] =
            (ws4[0] + ws4[1] + ws4[2] + ws4[3]) * (1.f / 4096.f);
}

// ---------------------------------------------------------------- per-head EMA + alpha (global)
__global__ __launch_bounds__(256) void k_alpha(const float* __restrict__ cs,
                                               const float* __restrict__ ema0,
                                               const float* __restrict__ l2ab,
                                               const float* __restrict__ l2b,
                                               float* __restrict__ alpha) {
    int h = blockIdx.x, tid = threadIdx.x;
    int b = tid >> 7, n = tid & 127;
    int gi = (b * 24 + h) * 128 + n;
    float v = cs[gi];
    float s = v;
    for (int off = 32; off; off >>= 1) s += __shfl_xor(s, off, 64);
    __shared__ float ws4[4];
    int lane = tid & 63, wv = tid >> 6;
    if (lane == 0) ws4[wv] = s;
    __syncthreads();
    float total = ws4[0] + ws4[1] + ws4[2] + ws4[3];
    float ema = 0.99f * ema0[h] + 0.01f * (total * (1.f / 256.f));
    float ab = 1.f - exp2f(clampf(l2ab[h], -3.32f, -0.015f));
    float beta = exp2f(clampf(l2b[h], -2.f, 2.f));
    float nz = v / (ema + 1e-6f);
    float boost = fmaxf(tanhf(beta * nz), 0.f);
    alpha[gi] = clampf(ab + (1.f - ab) * boost, 0.01f, 0.999f);
}

// ---------------------------------------------------------------- intra-chunk: Y_intra = (L ∘ C B^T) X
__global__ __launch_bounds__(256) void k_intra(const bf16* __restrict__ xp,
                                               const bf16* __restrict__ xc,
                                               const float* __restrict__ invB,
                                               const float* __restrict__ invC,
                                               const float* __restrict__ Aarr,
                                               const float* __restrict__ alpha,
                                               bf16* __restrict__ ybuf,
                                               int b, int l0) {
    int g = blockIdx.x;
    int h = g >> 5, nl = g & 31;
    int t0l = nl * 64;
    float alp = alpha[(size_t)(b * 24 + h) * 128 + (l0 >> 6) + nl];
    __shared__ float Ct[64][68];   // [s][i]
    __shared__ float Bt[64][68];   // [s][j] -> later M^T[j][i]
    __shared__ float Xn[64][68];   // [c][d]
    __shared__ float Acs[64];
    int tid = threadIdx.x;
    if (tid < 64) {
        float a = Aarr[(size_t)(t0l + tid) * 24 + h] * (1.f - alp);
        for (int off = 1; off < 64; off <<= 1) {
            float u = __shfl_up(a, off, 64);
            if (tid >= off) a += u;
        }
        Acs[tid] = a;
    }
    int s = tid & 63, cw0 = tid >> 6;
    for (int it = 0; it < 16; ++it) {
        int c = cw0 + (it << 2);
        int t = t0l + c;
        const bf16* bp = xp + (size_t)t * NPROJ + h * 129;
        Bt[s][c] = bf2f(bp[1 + s]) * invB[t * 24 + h];
        Ct[s][c] = bf2f(bp[65 + s]) * invC[t * 24 + h];
        Xn[c][s] = bf2f(xc[(size_t)t * DINNER + h * 64 + s]);
    }
    __syncthreads();
    int i0 = (tid >> 4) << 2, j0 = (tid & 15) << 2;
    float cb[4][4] = {};
    for (int ss = 0; ss < 64; ++ss) {
        const float4 c_ = *(const float4*)&Ct[ss][i0];
        const float4 b_ = *(const float4*)&Bt[ss][j0];
        const float cr[4] = {c_.x, c_.y, c_.z, c_.w};
        const float br[4] = {b_.x, b_.y, b_.z, b_.w};
#pragma unroll
        for (int r = 0; r < 4; ++r)
#pragma unroll
            for (int q = 0; q < 4; ++q) cb[r][q] += cr[r] * br[q];
    }
    __syncthreads();
#pragma unroll
    for (int r = 0; r < 4; ++r) {
        float ai = Acs[i0 + r];
#pragma unroll
        for (int q = 0; q < 4; ++q) {
            int j = j0 + q;
            float m = (j <= i0 + r) ? expf(ai - Acs[j]) * cb[r][q] : 0.f;
            Bt[j][i0 + r] = m;
        }
    }
    __syncthreads();
    float y[4][4] = {};
    for (int jj = 0; jj < 64; ++jj) {
        const float4 m_ = *(const float4*)&Bt[jj][i0];
        const float4 x_ = *(const float4*)&Xn[jj][j0];
        const float mr[4] = {m_.x, m_.y, m_.z, m_.w};
        const float xr[4] = {x_.x, x_.y, x_.z, x_.w};
#pragma unroll
        for (int r = 0; r < 4; ++r)
#pragma unroll
            for (int q = 0; q < 4; ++q) y[r][q] += mr[r] * xr[q];
    }
#pragma unroll
    for (int r = 0; r < 4; ++r) {
        int t = t0l + i0 + r;
        st4(&ybuf[(size_t)t * DINNER + h * 64 + j0],
            make_float4(y[r][0], y[r][1], y[r][2], y[r][3]));
    }
}

// ---------------------------------------------------------------- h_chunk_final + decay_chunk
__global__ __launch_bounds__(256) void k_hchunk(const bf16* __restrict__ xp,
                                                const bf16* __restrict__ xc,
                                                const float* __restrict__ invB,
                                                const float* __restrict__ Aarr,
                                                const float* __restrict__ alpha,
                                                bf16* __restrict__ hf,
                                                float* __restrict__ dchunk,
                                                int b, int l0) {
    int g = blockIdx.x;
    int h = g >> 5, nl = g & 31;
    int t0l = nl * 64;
    size_t gidx = (size_t)(b * 24 + h) * 128 + (l0 >> 6) + nl;
    float alp = alpha[gidx];
    __shared__ float Bn[64][68];
    __shared__ float Xn[64][68];
    __shared__ float dte[64];
    int tid = threadIdx.x;
    if (tid < 64) {
        float a = Aarr[(size_t)(t0l + tid) * 24 + h] * (1.f - alp);
        for (int off = 1; off < 64; off <<= 1) {
            float u = __shfl_up(a, off, 64);
            if (tid >= off) a += u;
        }
        float total = __shfl(a, 63, 64);
        dte[tid] = expf(total - a);
        if (tid == 0) dchunk[gidx] = expf(total);
    }
    int s = tid & 63, cw0 = tid >> 6;
    for (int it = 0; it < 16; ++it) {
        int c = cw0 + (it << 2);
        int t = t0l + c;
        Bn[c][s] = bf2f(xp[(size_t)t * NPROJ + h * 129 + 1 + s]) * invB[t * 24 + h];
        Xn[c][s] = bf2f(xc[(size_t)t * DINNER + h * 64 + s]);
    }
    __syncthreads();
    int s0 = (tid >> 4) << 2, d0 = (tid & 15) << 2;
    float acc[4][4] = {};
    for (int c = 0; c < 64; ++c) {
        float w = dte[c];
        const float4 b_ = *(const float4*)&Bn[c][s0];
        const float4 x_ = *(const float4*)&Xn[c][d0];
        const float br[4] = {w * b_.x, w * b_.y, w * b_.z, w * b_.w};
        const float xr[4] = {x_.x, x_.y, x_.z, x_.w};
#pragma unroll
        for (int r = 0; r < 4; ++r)
#pragma unroll
            for (int q = 0; q < 4; ++q) acc[r][q] += br[r] * xr[q];
    }
#pragma unroll
    for (int r = 0; r < 4; ++r) {
        st4(&hf[(size_t)(h * SEG_CH + nl) * 4096 + (size_t)(s0 + r) * 64 + d0],
            make_float4(acc[r][0], acc[r][1], acc[r][2], acc[r][3]));
    }
}

// ---------------------------------------------------------------- chunk scan within segment, carry across segments
__global__ __launch_bounds__(256) void k_scan(bf16* __restrict__ hf,
                                              const float* __restrict__ dchunk,
                                              float* __restrict__ carry,
                                              int b, int l0) {
    int h = blockIdx.x >> 4;                        // 0..23
    int e = ((blockIdx.x & 15) << 8) + threadIdx.x; // 0..4095
    int bh = b * 24 + h;
    float c = (l0 == 0) ? 0.f : carry[(size_t)bh * 4096 + e];
    for (int nl = 0; nl < SEG_CH; ++nl) {
        float dc = dchunk[(size_t)bh * 128 + (l0 >> 6) + nl];
        size_t a = (size_t)(h * SEG_CH + nl) * 4096 + e;
        float v = bf2f(hf[a]);
        hf[a] = f2bf(c);
        c = dc * c + v;
    }
    carry[(size_t)bh * 4096 + e] = c;
}

// ---------------------------------------------------------------- Y_inter + gate (in place on ybuf)
__global__ __launch_bounds__(256) void k_inter(const bf16* __restrict__ xp,
                                               const float* __restrict__ invC,
                                               const float* __restrict__ Aarr,
                                               const float* __restrict__ alpha,
                                               const bf16* __restrict__ hf,
                                               const bf16* __restrict__ zbuf,
                                               bf16* __restrict__ ybuf,
                                               int b, int l0) {
    int g = blockIdx.x;
    int h = g >> 5, nl = g & 31;
    int t0l = nl * 64;
    float alp = alpha[(size_t)(b * 24 + h) * 128 + (l0 >> 6) + nl];
    __shared__ float Ct[64][68];   // [s][i]
    __shared__ float Hs[64][68];   // [s][d]
    __shared__ float dfs[64];
    int tid = threadIdx.x;
    if (tid < 64) {
        float a = Aarr[(size_t)(t0l + tid) * 24 + h] * (1.f - alp);
        for (int off = 1; off < 64; off <<= 1) {
            float u = __shfl_up(a, off, 64);
            if (tid >= off) a += u;
        }
        dfs[tid] = expf(a);
    }
    int s = tid & 63, cw0 = tid >> 6;
    for (int it = 0; it < 16; ++it) {
        int row = cw0 + (it << 2);
        int t = t0l + row;
        Ct[s][row] = bf2f(xp[(size_t)t * NPROJ + h * 129 + 65 + s]) * invC[t * 24 + h];
        Hs[row][s] = bf2f(hf[(size_t)(h * SEG_CH + nl) * 4096 + (size_t)row * 64 + s]);
    }
    __syncthreads();
    int i0 = (tid >> 4) << 2, d0 = (tid & 15) << 2;
    float acc[4][4] = {};
    for (int ss = 0; ss < 64; ++ss) {
        const float4 c_ = *(const float4*)&Ct[ss][i0];
        const float4 h_ = *(const float4*)&Hs[ss][d0];
        const float cr[4] = {c_.x, c_.y, c_.z, c_.w};
        const float hr[4] = {h_.x, h_.y, h_.z, h_.w};
#pragma unroll
        for (int r = 0; r < 4; ++r)
#pragma unroll
            for (int q = 0; q < 4; ++q) acc[r][q] += cr[r] * hr[q];
    }
#pragma unroll
    for (int r = 0; r < 4; ++r) {
        int t = t0l + i0 + r;
        float df = dfs[i0 + r];
        size_t yoff = (size_t)t * DINNER + h * 64 + d0;
#pragma unroll
        for (int q = 0; q < 4; ++q) {
            float Y = clampf(bf2f(ybuf[yoff + q]) + df * acc[r][q], -100.f, 100.f);
            float zz = bf2f(zbuf[yoff + q]);
            ybuf[yoff + q] = f2bf(Y / (1.f + expf(-zz)));
        }
    }
}

// ---------------------------------------------------------------- launch
extern "C" void kernel_launch(void* const* d_in, const int* in_sizes, int n_in,
                              void* d_out, int out_size, void* d_ws, size_t ws_size,
                              hipStream_t stream) {
    const float* hs     = (const float*)d_in[0];
    const float* norm_w = (const float*)d_in[1];
    const float* w1     = (const float*)d_in[2];
    const float* b1     = (const float*)d_in[3];
    const float* cw     = (const float*)d_in[4];
    const float* cbias  = (const float*)d_in[5];
    const float* w2     = (const float*)d_in[6];
    const float* b2     = (const float*)d_in[7];
    const float* A_log  = (const float*)d_in[8];
    const float* l2ab   = (const float*)d_in[9];
    const float* l2b    = (const float*)d_in[10];
    const float* ema0   = (const float*)d_in[11];
    const float* w3     = (const float*)d_in[12];
    const float* b3     = (const float*)d_in[13];
    const float* rg     = (const float*)d_in[14];
    float* out = (float*)d_out;

    // ---- workspace layout (~37.5 MiB total)
    char* base = (char*)d_ws;
    size_t off = 0;
    auto alloc = [&](size_t bytes) -> void* {
        void* p = base + off;
        off += (bytes + 255) & ~(size_t)255;
        return p;
    };
    bf16* xbuf  = (bf16*)alloc((size_t)SEG_T * DINNER * 2);
    bf16* zbuf  = (bf16*)alloc((size_t)SEG_T * DINNER * 2);
    bf16* xc    = (bf16*)alloc((size_t)SEG_T * DINNER * 2);
    bf16* ybuf  = (bf16*)alloc((size_t)SEG_T * DINNER * 2);
    bf16* xp    = (bf16*)alloc((size_t)SEG_T * NPROJ * 2);
    bf16* xhalo = (bf16*)alloc((size_t)2 * 3 * DINNER * 2);
    float* Aarr = (float*)alloc((size_t)SEG_T * 24 * 4);
    float* invB = (float*)alloc((size_t)SEG_T * 24 * 4);
    float* invC = (float*)alloc((size_t)SEG_T * 24 * 4);
    float* cs   = (float*)alloc((size_t)6144 * 4);
    float* alp  = (float*)alloc((size_t)6144 * 4);
    float* dch  = (float*)alloc((size_t)6144 * 4);
    float* carry= (float*)alloc((size_t)48 * 4096 * 4);

    const dim3 gX(DINNER / 64, SEG_T / 64);          // x/z GEMM grid
    const dim3 gP((NPROJ + 63) / 64, SEG_T / 64);    // x_proj grid
    const dim3 gO(DMODEL / 64, SEG_T / 64);          // out_proj grid

    // ---------------- phase 1: surprise for all segments
    for (int s = 0; s < NSEG; ++s) {
        size_t t0 = (size_t)s * SEG_T;
        int l0 = (int)(t0 & (L_SEQ - 1));
        int b  = (int)(t0 >> 13);
        float* xn = (float*)((char*)d_out + t0 * DMODEL * 4);
        const float* hseg = hs + t0 * DMODEL;
        k_rmsnorm<<<SEG_T, 256, 0, stream>>>(hseg, norm_w, xn);
        k_gemm<float, bf16, 0><<<gX, 256, 0, stream>>>(xn, w1, b1, xbuf,
                                                       SEG_T, DINNER, DMODEL, nullptr, nullptr);
        k_save_halo<<<18, 256, 0, stream>>>(xbuf, xhalo + (size_t)((s + 1) & 1) * 3 * DINNER);
        k_conv_silu<<<dim3(DINNER / 256, SEG_T), 256, 0, stream>>>(
            xbuf, xhalo + (size_t)(s & 1) * 3 * DINNER, cw, cbias, xc, l0);
        k_gemm<bf16, bf16, 0><<<gP, 256, 0, stream>>>(xc, w2, b2, xp,
                                                      SEG_T, NPROJ, DINNER, nullptr, nullptr);
        k_prep<<<SEG_T * 24 / 4, 256, 0, stream>>>(xp, A_log, Aarr, invB, invC);
        k_surprise<<<768, 256, 0, stream>>>(xp, xc, invB, cs, b, l0);
    }
    k_alpha<<<24, 256, 0, stream>>>(cs, ema0, l2ab, l2b, alp);

    // ---------------- phase 2: SSM + output per segment
    for (int s = 0; s < NSEG; ++s) {
        size_t t0 = (size_t)s * SEG_T;
        int l0 = (int)(t0 & (L_SEQ - 1));
        int b  = (int)(t0 >> 13);
        float* xn = (float*)((char*)d_out + t0 * DMODEL * 4);  // persists from phase 1
        bf16* hf  = (bf16*)((char*)d_out + t0 * DMODEL * 4);   // reuses region after xn dead
        const float* hseg = hs + t0 * DMODEL;
        k_gemm<float, bf16, 0><<<gX, 256, 0, stream>>>(xn, w1, b1, xbuf,
                                                       SEG_T, DINNER, DMODEL, nullptr, nullptr);
        k_gemm<float, bf16, 0><<<gX, 256, 0, stream>>>(xn, w1 + (size_t)DINNER * DMODEL,
                                                       b1 + DINNER, zbuf,
                                                       SEG_T, DINNER, DMODEL, nullptr, nullptr);
        k_save_halo<<<18, 256, 0, stream>>>(xbuf, xhalo + (size_t)((s + 1) & 1) * 3 * DINNER);
        k_conv_silu<<<dim3(DINNER / 256, SEG_T), 256, 0, stream>>>(
            xbuf, xhalo + (size_t)(s & 1) * 3 * DINNER, cw, cbias, xc, l0);
        k_gemm<bf16, bf16, 0><<<gP, 256, 0, stream>>>(xc, w2, b2, xp,
                                                      SEG_T, NPROJ, DINNER, nullptr, nullptr);
        k_prep<<<SEG_T * 24 / 4, 256, 0, stream>>>(xp, A_log, Aarr, invB, invC);
        k_intra<<<768, 256, 0, stream>>>(xp, xc, invB, invC, Aarr, alp, ybuf, b, l0);
        k_hchunk<<<768, 256, 0, stream>>>(xp, xc, invB, Aarr, alp, hf, dch, b, l0);
        k_scan<<<384, 256, 0, stream>>>(hf, dch, carry, b, l0);
        k_inter<<<768, 256, 0, stream>>>(xp, invC, Aarr, alp, hf, zbuf, ybuf, b, l0);
        k_gemm<bf16, float, 1><<<gO, 256, 0, stream>>>(ybuf, w3, b3, out + t0 * DMODEL,
                                                       SEG_T, DMODEL, DINNER, hseg, rg);
    }
}

// Round 4
// 3528.053 us; speedup vs baseline: 2.2650x; 2.2650x over previous
//
#include <hip/hip_runtime.h>
#include <hip/hip_bf16.h>
#include <cstdint>
#include <cstddef>

#define L_SEQ   8192
#define DMODEL  768
#define NHEADS  24
#define DINNER  1536
#define NPROJ   3096      /* 24 * 129 */
#define NTOK    16384
#define SEG_T   2048      /* tokens per segment */
#define NSEG    8
#define SEG_CH  32        /* chunks per segment */
#define RMS_EPS 1.1920929e-07f

typedef __hip_bfloat16 bf16;
typedef __attribute__((ext_vector_type(8))) short bf8v;   // 8 bf16 (4 VGPRs) MFMA operand
typedef __attribute__((ext_vector_type(4))) float f4v;    // MFMA accumulator

__device__ __forceinline__ float clampf(float x, float lo, float hi) {
    return fminf(fmaxf(x, lo), hi);
}
__device__ __forceinline__ float bf2f(bf16 v) { return __bfloat162float(v); }
__device__ __forceinline__ bf16  f2bf(float v) { return __float2bfloat16(v); }
__device__ __forceinline__ short f2bs(float v) {
    bf16 b = __float2bfloat16(v);
    return *reinterpret_cast<short*>(&b);
}
__device__ __forceinline__ void st1(float* p, float v) { *p = v; }
__device__ __forceinline__ void st1(bf16* p, float v) { *p = f2bf(v); }
__device__ __forceinline__ void st4(float* p, float4 v) { *(float4*)p = v; }
__device__ __forceinline__ void st4(bf16* p, float4 v) {
    p[0] = f2bf(v.x); p[1] = f2bf(v.y); p[2] = f2bf(v.z); p[3] = f2bf(v.w);
}

// ---------------------------------------------------------------- RMSNorm (segment: T rows, f32 out)
__global__ __launch_bounds__(256) void k_rmsnorm(const float* __restrict__ hs,
                                                 const float* __restrict__ w,
                                                 float* __restrict__ xn) {
    int t = blockIdx.x;
    const float* p = hs + (size_t)t * DMODEL;
    float s = 0.f;
    for (int i = threadIdx.x; i < DMODEL; i += 256) { float v = p[i]; s += v * v; }
    for (int off = 32; off; off >>= 1) s += __shfl_xor(s, off, 64);
    __shared__ float ws4[4];
    int lane = threadIdx.x & 63, wv = threadIdx.x >> 6;
    if (lane == 0) ws4[wv] = s;
    __syncthreads();
    s = ws4[0] + ws4[1] + ws4[2] + ws4[3];
    float r = 1.0f / sqrtf(s * (1.0f / DMODEL) + RMS_EPS);
    float* o = xn + (size_t)t * DMODEL;
    for (int i = threadIdx.x; i < DMODEL; i += 256) o[i] = p[i] * r * w[i];
}

// ---------------------------------------------------------------- MFMA GEMM  C[M,N] = A[M,K] @ B[N,K]^T + bias
// A: f32 or bf16 activations; B: f32 weights (converted to bf16 in staging).
// Tile 128x128, BK=32, 4 waves (64x64 each), mfma_f32_16x16x32_bf16.
// EPI 0: C = acc + bias     EPI 1: C = resid + clip(acc + bias, ±100) * (*gatep)
template <typename TA, typename TC, int EPI>
__global__ __launch_bounds__(256) void k_mgemm(const TA* __restrict__ A,
                                               const float* __restrict__ B,
                                               const float* __restrict__ bias,
                                               TC* __restrict__ C,
                                               int M, int N, int K,
                                               const float* __restrict__ resid,
                                               const float* __restrict__ gatep) {
    constexpr int LDR = 40;                 // padded LDS row (shorts): spreads frag reads over banks
    __shared__ short As[128 * LDR];
    __shared__ short Bs[128 * LDR];
    int tid = threadIdx.x;
    int lane = tid & 63, wid = tid >> 6;
    int m0 = blockIdx.y * 128, n0 = blockIdx.x * 128;
    int wm = (wid >> 1) << 6, wn = (wid & 1) << 6;   // wave sub-tile origin
    int srow = tid >> 2, skc = (tid & 3) << 3;       // staging: row 0..63, k-offset {0,8,16,24}

    f4v acc[4][4];
#pragma unroll
    for (int i = 0; i < 4; ++i)
#pragma unroll
        for (int j = 0; j < 4; ++j) acc[i][j] = (f4v){0.f, 0.f, 0.f, 0.f};

    for (int k0 = 0; k0 < K; k0 += 32) {
        __syncthreads();
        // ---- stage A tile (rows m0..m0+127, cols k0..k0+31)
#pragma unroll
        for (int half = 0; half < 2; ++half) {
            int r = srow + (half << 6);
            short* dst = &As[r * LDR + skc];
            const TA* src = A + (size_t)(m0 + r) * K + k0 + skc;
            if constexpr (sizeof(TA) == 4) {
                float4 x0 = *(const float4*)(const void*)src;
                float4 x1 = *(const float4*)(const void*)(src + 4);
                bf8v t;
                t[0] = f2bs(x0.x); t[1] = f2bs(x0.y); t[2] = f2bs(x0.z); t[3] = f2bs(x0.w);
                t[4] = f2bs(x1.x); t[5] = f2bs(x1.y); t[6] = f2bs(x1.z); t[7] = f2bs(x1.w);
                *(bf8v*)dst = t;
            } else {
                *(uint4*)dst = *(const uint4*)(const void*)src;
            }
        }
        // ---- stage B tile (weight rows n0..n0+127, f32 -> bf16, zero-fill OOB)
#pragma unroll
        for (int half = 0; half < 2; ++half) {
            int r = srow + (half << 6);
            int nrow = n0 + r;
            bf8v t = (bf8v){0, 0, 0, 0, 0, 0, 0, 0};
            if (nrow < N) {
                const float* src = B + (size_t)nrow * K + k0 + skc;
                float4 x0 = *(const float4*)src;
                float4 x1 = *(const float4*)(src + 4);
                t[0] = f2bs(x0.x); t[1] = f2bs(x0.y); t[2] = f2bs(x0.z); t[3] = f2bs(x0.w);
                t[4] = f2bs(x1.x); t[5] = f2bs(x1.y); t[6] = f2bs(x1.z); t[7] = f2bs(x1.w);
            }
            *(bf8v*)&Bs[r * LDR + skc] = t;
        }
        __syncthreads();
        // ---- fragments + MFMA
        int row16 = lane & 15, kg = (lane >> 4) << 3;
        bf8v af[4], bfv[4];
#pragma unroll
        for (int fm = 0; fm < 4; ++fm)
            af[fm] = *(const bf8v*)&As[(wm + (fm << 4) + row16) * LDR + kg];
#pragma unroll
        for (int fn = 0; fn < 4; ++fn)
            bfv[fn] = *(const bf8v*)&Bs[(wn + (fn << 4) + row16) * LDR + kg];
#pragma unroll
        for (int fm = 0; fm < 4; ++fm)
#pragma unroll
            for (int fn = 0; fn < 4; ++fn)
                acc[fm][fn] = __builtin_amdgcn_mfma_f32_16x16x32_bf16(
                    af[fm], bfv[fn], acc[fm][fn], 0, 0, 0);
    }

    // ---- epilogue: C/D layout col = lane&15, row = (lane>>4)*4 + r
    float gate = (EPI == 1) ? *gatep : 0.f;
    int rbase = m0 + wm + ((lane >> 4) << 2);
#pragma unroll
    for (int fn = 0; fn < 4; ++fn) {
        int col = n0 + wn + (fn << 4) + (lane & 15);
        if (col >= N) continue;
        float bc = bias[col];
#pragma unroll
        for (int fm = 0; fm < 4; ++fm) {
#pragma unroll
            for (int r = 0; r < 4; ++r) {
                int row = rbase + (fm << 4) + r;
                float v = acc[fm][fn][r] + bc;
                if (EPI == 1)
                    v = resid[(size_t)row * N + col] + clampf(v, -100.f, 100.f) * gate;
                st1(&C[(size_t)row * N + col], v);
            }
        }
    }
}

// ---------------------------------------------------------------- save last 3 rows of x for next segment's conv halo
__global__ __launch_bounds__(256) void k_save_halo(const bf16* __restrict__ x,
                                                   bf16* __restrict__ dst) {
    int i = blockIdx.x * 256 + threadIdx.x;
    if (i < 3 * DINNER) dst[i] = x[(size_t)(SEG_T - 3) * DINNER + i];
}

// ---------------------------------------------------------------- depthwise causal conv (k=4) + SiLU, segment-local
__global__ __launch_bounds__(256) void k_conv_silu(const bf16* __restrict__ x,
                                                   const bf16* __restrict__ xh,
                                                   const float* __restrict__ cw,
                                                   const float* __restrict__ cb,
                                                   bf16* __restrict__ xc,
                                                   int l0) {
    int c = blockIdx.x * 256 + threadIdx.x;   // < DINNER
    int r = blockIdx.y;                       // 0..SEG_T-1
    int l = l0 + r;
    float acc = cb[c];
#pragma unroll
    for (int k = 0; k < 4; ++k) {
        int lp = l - 3 + k;
        if (lp < 0) continue;
        float v = (lp < l0) ? bf2f(xh[(size_t)(lp - l0 + 3) * DINNER + c])
                            : bf2f(x[(size_t)(lp - l0) * DINNER + c]);
        acc += cw[c * 4 + k] * v;
    }
    float sig = 1.f / (1.f + expf(-acc));
    xc[(size_t)r * DINNER + c] = f2bf(acc * sig);
}

// ---------------------------------------------------------------- per-(t,h): A value, 1/||B||, 1/||C|| (segment-local)
__global__ __launch_bounds__(256) void k_prep(const bf16* __restrict__ xp,
                                              const float* __restrict__ A_log,
                                              float* __restrict__ Aarr,
                                              float* __restrict__ invB,
                                              float* __restrict__ invC) {
    int wv = threadIdx.x >> 6, lane = threadIdx.x & 63;
    int idx = blockIdx.x * 4 + wv;            // t_local*24 + h, < SEG_T*24
    int t = idx / 24, h = idx - t * 24;
    const bf16* base = xp + (size_t)t * NPROJ + h * 129;
    float b = bf2f(base[1 + lane]), c = bf2f(base[65 + lane]);
    float sb = b * b, sc = c * c;
    for (int off = 32; off; off >>= 1) {
        sb += __shfl_xor(sb, off, 64);
        sc += __shfl_xor(sc, off, 64);
    }
    if (lane == 0) {
        invB[idx] = 1.f / fmaxf(sqrtf(sb), 1e-12f);
        invC[idx] = 1.f / fmaxf(sqrtf(sc), 1e-12f);
        float dt = clampf(bf2f(base[0]), -10.f, 10.f);
        float dts = clampf(log1pf(expf(dt)), 0.01f, 10.f);
        float A = clampf(A_log[h], -2.3f, -0.01f) * dts;
        Aarr[idx] = clampf(A, -20.f, -0.001f);
    }
}

// ---------------------------------------------------------------- chunk surprise (segment-local inputs, global cs)
__global__ __launch_bounds__(256) void k_surprise(const bf16* __restrict__ xp,
                                                  const bf16* __restrict__ xc,
                                                  const float* __restrict__ invB,
                                                  float* __restrict__ cs,
                                                  int b, int l0) {
    int g = blockIdx.x;                // 0..767
    int h = g >> 5, nl = g & 31;
    int t0l = nl * 64;
    __shared__ float Bs[64][68];
    __shared__ float Xs[64][68];
    int tid = threadIdx.x, s = tid & 63, cw0 = tid >> 6;
    for (int it = 0; it < 16; ++it) {
        int c = cw0 + (it << 2);
        int t = t0l + c;
        Bs[c][s] = bf2f(xp[(size_t)t * NPROJ + h * 129 + 1 + s]) * invB[t * 24 + h];
        Xs[c][s] = bf2f(xc[(size_t)t * DINNER + h * 64 + s]);
    }
    __syncthreads();
    int s0 = (tid >> 4) << 2, d0 = (tid & 15) << 2;
    float acc[4][4] = {};
    for (int c = 0; c < 64; ++c) {
        const float4 b_ = *(const float4*)&Bs[c][s0];
        const float4 x_ = *(const float4*)&Xs[c][d0];
        const float br[4] = {b_.x, b_.y, b_.z, b_.w};
        const float xr[4] = {x_.x, x_.y, x_.z, x_.w};
#pragma unroll
        for (int r = 0; r < 4; ++r)
#pragma unroll
            for (int q = 0; q < 4; ++q) acc[r][q] += br[r] * xr[q];
    }
    float ss = 0.f;
#pragma unroll
    for (int r = 0; r < 4; ++r)
#pragma unroll
        for (int q = 0; q < 4; ++q) ss += acc[r][q] * acc[r][q];
    for (int off = 32; off; off >>= 1) ss += __shfl_xor(ss, off, 64);
    __shared__ float ws4[4];
    int lane = tid & 63, wv = tid >> 6;
    if (lane == 0) ws4[wv] = ss;
    __syncthreads();
    if (tid == 0)
        cs[(size_t)(b * 24 + h) * 128 + (l0 >> 6) + nl] =
            (ws4[0] + ws4[1] + ws4[2] + ws4[3]) * (1.f / 4096.f);
}

// ---------------------------------------------------------------- per-head EMA + alpha (global)
__global__ __launch_bounds__(256) void k_alpha(const float* __restrict__ cs,
                                               const float* __restrict__ ema0,
                                               const float* __restrict__ l2ab,
                                               const float* __restrict__ l2b,
                                               float* __restrict__ alpha) {
    int h = blockIdx.x, tid = threadIdx.x;
    int b = tid >> 7, n = tid & 127;
    int gi = (b * 24 + h) * 128 + n;
    float v = cs[gi];
    float s = v;
    for (int off = 32; off; off >>= 1) s += __shfl_xor(s, off, 64);
    __shared__ float ws4[4];
    int lane = tid & 63, wv = tid >> 6;
    if (lane == 0) ws4[wv] = s;
    __syncthreads();
    float total = ws4[0] + ws4[1] + ws4[2] + ws4[3];
    float ema = 0.99f * ema0[h] + 0.01f * (total * (1.f / 256.f));
    float ab = 1.f - exp2f(clampf(l2ab[h], -3.32f, -0.015f));
    float beta = exp2f(clampf(l2b[h], -2.f, 2.f));
    float nz = v / (ema + 1e-6f);
    float boost = fmaxf(tanhf(beta * nz), 0.f);
    alpha[gi] = clampf(ab + (1.f - ab) * boost, 0.01f, 0.999f);
}

// ---------------------------------------------------------------- intra-chunk: Y_intra = (L ∘ C B^T) X
__global__ __launch_bounds__(256) void k_intra(const bf16* __restrict__ xp,
                                               const bf16* __restrict__ xc,
                                               const float* __restrict__ invB,
                                               const float* __restrict__ invC,
                                               const float* __restrict__ Aarr,
                                               const float* __restrict__ alpha,
                                               bf16* __restrict__ ybuf,
                                               int b, int l0) {
    int g = blockIdx.x;
    int h = g >> 5, nl = g & 31;
    int t0l = nl * 64;
    float alp = alpha[(size_t)(b * 24 + h) * 128 + (l0 >> 6) + nl];
    __shared__ float Ct[64][68];   // [s][i]
    __shared__ float Bt[64][68];   // [s][j] -> later M^T[j][i]
    __shared__ float Xn[64][68];   // [c][d]
    __shared__ float Acs[64];
    int tid = threadIdx.x;
    if (tid < 64) {
        float a = Aarr[(size_t)(t0l + tid) * 24 + h] * (1.f - alp);
        for (int off = 1; off < 64; off <<= 1) {
            float u = __shfl_up(a, off, 64);
            if (tid >= off) a += u;
        }
        Acs[tid] = a;
    }
    int s = tid & 63, cw0 = tid >> 6;
    for (int it = 0; it < 16; ++it) {
        int c = cw0 + (it << 2);
        int t = t0l + c;
        const bf16* bp = xp + (size_t)t * NPROJ + h * 129;
        Bt[s][c] = bf2f(bp[1 + s]) * invB[t * 24 + h];
        Ct[s][c] = bf2f(bp[65 + s]) * invC[t * 24 + h];
        Xn[c][s] = bf2f(xc[(size_t)t * DINNER + h * 64 + s]);
    }
    __syncthreads();
    int i0 = (tid >> 4) << 2, j0 = (tid & 15) << 2;
    float cb[4][4] = {};
    for (int ss = 0; ss < 64; ++ss) {
        const float4 c_ = *(const float4*)&Ct[ss][i0];
        const float4 b_ = *(const float4*)&Bt[ss][j0];
        const float cr[4] = {c_.x, c_.y, c_.z, c_.w};
        const float br[4] = {b_.x, b_.y, b_.z, b_.w};
#pragma unroll
        for (int r = 0; r < 4; ++r)
#pragma unroll
            for (int q = 0; q < 4; ++q) cb[r][q] += cr[r] * br[q];
    }
    __syncthreads();
#pragma unroll
    for (int r = 0; r < 4; ++r) {
        float ai = Acs[i0 + r];
#pragma unroll
        for (int q = 0; q < 4; ++q) {
            int j = j0 + q;
            float m = (j <= i0 + r) ? expf(ai - Acs[j]) * cb[r][q] : 0.f;
            Bt[j][i0 + r] = m;
        }
    }
    __syncthreads();
    float y[4][4] = {};
    for (int jj = 0; jj < 64; ++jj) {
        const float4 m_ = *(const float4*)&Bt[jj][i0];
        const float4 x_ = *(const float4*)&Xn[jj][j0];
        const float mr[4] = {m_.x, m_.y, m_.z, m_.w};
        const float xr[4] = {x_.x, x_.y, x_.z, x_.w};
#pragma unroll
        for (int r = 0; r < 4; ++r)
#pragma unroll
            for (int q = 0; q < 4; ++q) y[r][q] += mr[r] * xr[q];
    }
#pragma unroll
    for (int r = 0; r < 4; ++r) {
        int t = t0l + i0 + r;
        st4(&ybuf[(size_t)t * DINNER + h * 64 + j0],
            make_float4(y[r][0], y[r][1], y[r][2], y[r][3]));
    }
}

// ---------------------------------------------------------------- h_chunk_final + decay_chunk
__global__ __launch_bounds__(256) void k_hchunk(const bf16* __restrict__ xp,
                                                const bf16* __restrict__ xc,
                                                const float* __restrict__ invB,
                                                const float* __restrict__ Aarr,
                                                const float* __restrict__ alpha,
                                                bf16* __restrict__ hf,
                                                float* __restrict__ dchunk,
                                                int b, int l0) {
    int g = blockIdx.x;
    int h = g >> 5, nl = g & 31;
    int t0l = nl * 64;
    size_t gidx = (size_t)(b * 24 + h) * 128 + (l0 >> 6) + nl;
    float alp = alpha[gidx];
    __shared__ float Bn[64][68];
    __shared__ float Xn[64][68];
    __shared__ float dte[64];
    int tid = threadIdx.x;
    if (tid < 64) {
        float a = Aarr[(size_t)(t0l + tid) * 24 + h] * (1.f - alp);
        for (int off = 1; off < 64; off <<= 1) {
            float u = __shfl_up(a, off, 64);
            if (tid >= off) a += u;
        }
        float total = __shfl(a, 63, 64);
        dte[tid] = expf(total - a);
        if (tid == 0) dchunk[gidx] = expf(total);
    }
    int s = tid & 63, cw0 = tid >> 6;
    for (int it = 0; it < 16; ++it) {
        int c = cw0 + (it << 2);
        int t = t0l + c;
        Bn[c][s] = bf2f(xp[(size_t)t * NPROJ + h * 129 + 1 + s]) * invB[t * 24 + h];
        Xn[c][s] = bf2f(xc[(size_t)t * DINNER + h * 64 + s]);
    }
    __syncthreads();
    int s0 = (tid >> 4) << 2, d0 = (tid & 15) << 2;
    float acc[4][4] = {};
    for (int c = 0; c < 64; ++c) {
        float w = dte[c];
        const float4 b_ = *(const float4*)&Bn[c][s0];
        const float4 x_ = *(const float4*)&Xn[c][d0];
        const float br[4] = {w * b_.x, w * b_.y, w * b_.z, w * b_.w};
        const float xr[4] = {x_.x, x_.y, x_.z, x_.w};
#pragma unroll
        for (int r = 0; r < 4; ++r)
#pragma unroll
            for (int q = 0; q < 4; ++q) acc[r][q] += br[r] * xr[q];
    }
#pragma unroll
    for (int r = 0; r < 4; ++r) {
        st4(&hf[(size_t)(h * SEG_CH + nl) * 4096 + (size_t)(s0 + r) * 64 + d0],
            make_float4(acc[r][0], acc[r][1], acc[r][2], acc[r][3]));
    }
}

// ---------------------------------------------------------------- chunk scan within segment, carry across segments
__global__ __launch_bounds__(256) void k_scan(bf16* __restrict__ hf,
                                              const float* __restrict__ dchunk,
                                              float* __restrict__ carry,
                                              int b, int l0) {
    int h = blockIdx.x >> 4;                        // 0..23
    int e = ((blockIdx.x & 15) << 8) + threadIdx.x; // 0..4095
    int bh = b * 24 + h;
    float c = (l0 == 0) ? 0.f : carry[(size_t)bh * 4096 + e];
    for (int nl = 0; nl < SEG_CH; ++nl) {
        float dc = dchunk[(size_t)bh * 128 + (l0 >> 6) + nl];
        size_t a = (size_t)(h * SEG_CH + nl) * 4096 + e;
        float v = bf2f(hf[a]);
        hf[a] = f2bf(c);
        c = dc * c + v;
    }
    carry[(size_t)bh * 4096 + e] = c;
}

// ---------------------------------------------------------------- Y_inter + gate (in place on ybuf)
__global__ __launch_bounds__(256) void k_inter(const bf16* __restrict__ xp,
                                               const float* __restrict__ invC,
                                               const float* __restrict__ Aarr,
                                               const float* __restrict__ alpha,
                                               const bf16* __restrict__ hf,
                                               const bf16* __restrict__ zbuf,
                                               bf16* __restrict__ ybuf,
                                               int b, int l0) {
    int g = blockIdx.x;
    int h = g >> 5, nl = g & 31;
    int t0l = nl * 64;
    float alp = alpha[(size_t)(b * 24 + h) * 128 + (l0 >> 6) + nl];
    __shared__ float Ct[64][68];   // [s][i]
    __shared__ float Hs[64][68];   // [s][d]
    __shared__ float dfs[64];
    int tid = threadIdx.x;
    if (tid < 64) {
        float a = Aarr[(size_t)(t0l + tid) * 24 + h] * (1.f - alp);
        for (int off = 1; off < 64; off <<= 1) {
            float u = __shfl_up(a, off, 64);
            if (tid >= off) a += u;
        }
        dfs[tid] = expf(a);
    }
    int s = tid & 63, cw0 = tid >> 6;
    for (int it = 0; it < 16; ++it) {
        int row = cw0 + (it << 2);
        int t = t0l + row;
        Ct[s][row] = bf2f(xp[(size_t)t * NPROJ + h * 129 + 65 + s]) * invC[t * 24 + h];
        Hs[row][s] = bf2f(hf[(size_t)(h * SEG_CH + nl) * 4096 + (size_t)row * 64 + s]);
    }
    __syncthreads();
    int i0 = (tid >> 4) << 2, d0 = (tid & 15) << 2;
    float acc[4][4] = {};
    for (int ss = 0; ss < 64; ++ss) {
        const float4 c_ = *(const float4*)&Ct[ss][i0];
        const float4 h_ = *(const float4*)&Hs[ss][d0];
        const float cr[4] = {c_.x, c_.y, c_.z, c_.w};
        const float hr[4] = {h_.x, h_.y, h_.z, h_.w};
#pragma unroll
        for (int r = 0; r < 4; ++r)
#pragma unroll
            for (int q = 0; q < 4; ++q) acc[r][q] += cr[r] * hr[q];
    }
#pragma unroll
    for (int r = 0; r < 4; ++r) {
        int t = t0l + i0 + r;
        float df = dfs[i0 + r];
        size_t yoff = (size_t)t * DINNER + h * 64 + d0;
#pragma unroll
        for (int q = 0; q < 4; ++q) {
            float Y = clampf(bf2f(ybuf[yoff + q]) + df * acc[r][q], -100.f, 100.f);
            float zz = bf2f(zbuf[yoff + q]);
            ybuf[yoff + q] = f2bf(Y / (1.f + expf(-zz)));
        }
    }
}

// ---------------------------------------------------------------- launch
extern "C" void kernel_launch(void* const* d_in, const int* in_sizes, int n_in,
                              void* d_out, int out_size, void* d_ws, size_t ws_size,
                              hipStream_t stream) {
    const float* hs     = (const float*)d_in[0];
    const float* norm_w = (const float*)d_in[1];
    const float* w1     = (const float*)d_in[2];
    const float* b1     = (const float*)d_in[3];
    const float* cw     = (const float*)d_in[4];
    const float* cbias  = (const float*)d_in[5];
    const float* w2     = (const float*)d_in[6];
    const float* b2     = (const float*)d_in[7];
    const float* A_log  = (const float*)d_in[8];
    const float* l2ab   = (const float*)d_in[9];
    const float* l2b    = (const float*)d_in[10];
    const float* ema0   = (const float*)d_in[11];
    const float* w3     = (const float*)d_in[12];
    const float* b3     = (const float*)d_in[13];
    const float* rg     = (const float*)d_in[14];
    float* out = (float*)d_out;

    // ---- workspace layout (~37.5 MiB total)
    char* base = (char*)d_ws;
    size_t off = 0;
    auto alloc = [&](size_t bytes) -> void* {
        void* p = base + off;
        off += (bytes + 255) & ~(size_t)255;
        return p;
    };
    bf16* xbuf  = (bf16*)alloc((size_t)SEG_T * DINNER * 2);
    bf16* zbuf  = (bf16*)alloc((size_t)SEG_T * DINNER * 2);
    bf16* xc    = (bf16*)alloc((size_t)SEG_T * DINNER * 2);
    bf16* ybuf  = (bf16*)alloc((size_t)SEG_T * DINNER * 2);
    bf16* xp    = (bf16*)alloc((size_t)SEG_T * NPROJ * 2);
    bf16* xhalo = (bf16*)alloc((size_t)2 * 3 * DINNER * 2);
    float* Aarr = (float*)alloc((size_t)SEG_T * 24 * 4);
    float* invB = (float*)alloc((size_t)SEG_T * 24 * 4);
    float* invC = (float*)alloc((size_t)SEG_T * 24 * 4);
    float* cs   = (float*)alloc((size_t)6144 * 4);
    float* alp  = (float*)alloc((size_t)6144 * 4);
    float* dch  = (float*)alloc((size_t)6144 * 4);
    float* carry= (float*)alloc((size_t)48 * 4096 * 4);

    const dim3 gX(DINNER / 128, SEG_T / 128);            // 12 x 16
    const dim3 gP((NPROJ + 127) / 128, SEG_T / 128);     // 25 x 16
    const dim3 gO(DMODEL / 128, SEG_T / 128);            // 6 x 16

    // ---------------- phase 1: surprise for all segments
    for (int s = 0; s < NSEG; ++s) {
        size_t t0 = (size_t)s * SEG_T;
        int l0 = (int)(t0 & (L_SEQ - 1));
        int b  = (int)(t0 >> 13);
        float* xn = (float*)((char*)d_out + t0 * DMODEL * 4);
        const float* hseg = hs + t0 * DMODEL;
        k_rmsnorm<<<SEG_T, 256, 0, stream>>>(hseg, norm_w, xn);
        k_mgemm<float, bf16, 0><<<gX, 256, 0, stream>>>(xn, w1, b1, xbuf,
                                                        SEG_T, DINNER, DMODEL, nullptr, nullptr);
        k_save_halo<<<18, 256, 0, stream>>>(xbuf, xhalo + (size_t)((s + 1) & 1) * 3 * DINNER);
        k_conv_silu<<<dim3(DINNER / 256, SEG_T), 256, 0, stream>>>(
            xbuf, xhalo + (size_t)(s & 1) * 3 * DINNER, cw, cbias, xc, l0);
        k_mgemm<bf16, bf16, 0><<<gP, 256, 0, stream>>>(xc, w2, b2, xp,
                                                       SEG_T, NPROJ, DINNER, nullptr, nullptr);
        k_prep<<<SEG_T * 24 / 4, 256, 0, stream>>>(xp, A_log, Aarr, invB, invC);
        k_surprise<<<768, 256, 0, stream>>>(xp, xc, invB, cs, b, l0);
    }
    k_alpha<<<24, 256, 0, stream>>>(cs, ema0, l2ab, l2b, alp);

    // ---------------- phase 2: SSM + output per segment
    for (int s = 0; s < NSEG; ++s) {
        size_t t0 = (size_t)s * SEG_T;
        int l0 = (int)(t0 & (L_SEQ - 1));
        int b  = (int)(t0 >> 13);
        float* xn = (float*)((char*)d_out + t0 * DMODEL * 4);  // persists from phase 1
        bf16* hf  = (bf16*)((char*)d_out + t0 * DMODEL * 4);   // reuses region after xn dead
        const float* hseg = hs + t0 * DMODEL;
        k_mgemm<float, bf16, 0><<<gX, 256, 0, stream>>>(xn, w1, b1, xbuf,
                                                        SEG_T, DINNER, DMODEL, nullptr, nullptr);
        k_mgemm<float, bf16, 0><<<gX, 256, 0, stream>>>(xn, w1 + (size_t)DINNER * DMODEL,
                                                        b1 + DINNER, zbuf,
                                                        SEG_T, DINNER, DMODEL, nullptr, nullptr);
        k_save_halo<<<18, 256, 0, stream>>>(xbuf, xhalo + (size_t)((s + 1) & 1) * 3 * DINNER);
        k_conv_silu<<<dim3(DINNER / 256, SEG_T), 256, 0, stream>>>(
            xbuf, xhalo + (size_t)(s & 1) * 3 * DINNER, cw, cbias, xc, l0);
        k_mgemm<bf16, bf16, 0><<<gP, 256, 0, stream>>>(xc, w2, b2, xp,
                                                       SEG_T, NPROJ, DINNER, nullptr, nullptr);
        k_prep<<<SEG_T * 24 / 4, 256, 0, stream>>>(xp, A_log, Aarr, invB, invC);
        k_intra<<<768, 256, 0, stream>>>(xp, xc, invB, invC, Aarr, alp, ybuf, b, l0);
        k_hchunk<<<768, 256, 0, stream>>>(xp, xc, invB, Aarr, alp, hf, dch, b, l0);
        k_scan<<<384, 256, 0, stream>>>(hf, dch, carry, b, l0);
        k_inter<<<768, 256, 0, stream>>>(xp, invC, Aarr, alp, hf, zbuf, ybuf, b, l0);
        k_mgemm<bf16, float, 1><<<gO, 256, 0, stream>>>(ybuf, w3, b3, out + t0 * DMODEL,
                                                        SEG_T, DMODEL, DINNER, hseg, rg);
    }
}

// Round 5
// 1886.889 us; speedup vs baseline: 4.2350x; 1.8698x over previous
//
#include <hip/hip_runtime.h>
#include <hip/hip_bf16.h>
#include <cstdint>
#include <cstddef>

#define L_SEQ   8192
#define DMODEL  768
#define NHEADS  24
#define DINNER  1536
#define NPROJ   3096      /* 24 * 129 */
#define NTOK    16384
#define SEG_T   4096      /* tokens per segment */
#define NSEG    4
#define SEG_CH  64        /* chunks per segment */
#define RMS_EPS 1.1920929e-07f

typedef __hip_bfloat16 bf16;
typedef __attribute__((ext_vector_type(8))) short bf8v;   // 8 bf16 (4 VGPRs) MFMA operand
typedef __attribute__((ext_vector_type(4))) float f4v;    // MFMA accumulator

__device__ __forceinline__ float clampf(float x, float lo, float hi) {
    return fminf(fmaxf(x, lo), hi);
}
__device__ __forceinline__ float bf2f(bf16 v) { return __bfloat162float(v); }
__device__ __forceinline__ bf16  f2bf(float v) { return __float2bfloat16(v); }
__device__ __forceinline__ void st1(float* p, float v) { *p = v; }
__device__ __forceinline__ void st1(bf16* p, float v) { *p = f2bf(v); }
__device__ __forceinline__ void st4(float* p, float4 v) { *(float4*)p = v; }
__device__ __forceinline__ void st4(bf16* p, float4 v) {
    p[0] = f2bf(v.x); p[1] = f2bf(v.y); p[2] = f2bf(v.z); p[3] = f2bf(v.w);
}

// ---------------------------------------------------------------- f32 -> bf16 weight conversion (once per launch)
__global__ __launch_bounds__(256) void k_cvt(const float* __restrict__ s,
                                             bf16* __restrict__ d, int n4) {
    int i = blockIdx.x * 256 + threadIdx.x;
    if (i < n4) {
        float4 v = *(const float4*)&s[i * 4];
        st4(&d[i * 4], v);
    }
}

// ---------------------------------------------------------------- RMSNorm (f32 in, bf16 out)
__global__ __launch_bounds__(256) void k_rmsnorm(const float* __restrict__ hs,
                                                 const float* __restrict__ w,
                                                 bf16* __restrict__ xn) {
    int t = blockIdx.x;
    const float* p = hs + (size_t)t * DMODEL;
    float s = 0.f;
    for (int i = threadIdx.x; i < DMODEL; i += 256) { float v = p[i]; s += v * v; }
    for (int off = 32; off; off >>= 1) s += __shfl_xor(s, off, 64);
    __shared__ float ws4[4];
    int lane = threadIdx.x & 63, wv = threadIdx.x >> 6;
    if (lane == 0) ws4[wv] = s;
    __syncthreads();
    s = ws4[0] + ws4[1] + ws4[2] + ws4[3];
    float r = 1.0f / sqrtf(s * (1.0f / DMODEL) + RMS_EPS);
    bf16* o = xn + (size_t)t * DMODEL;
    for (int i = threadIdx.x; i < DMODEL; i += 256) o[i] = f2bf(p[i] * r * w[i]);
}

// ---------------------------------------------------------------- MFMA GEMM  C[M,N] = A[M,K] @ B[N,K]^T + bias
// All-bf16 operands. Tile 128x128, BK=32, 4 waves (64x64 each).
// XCD-aware block swizzle (caller guarantees gridDim.x*gridDim.y % 8 == 0).
// EPI 0: C = acc + bias     EPI 1: C = resid + clip(acc + bias, ±100) * (*gatep)
template <typename TC, int EPI>
__global__ __launch_bounds__(256) void k_mgemm(const bf16* __restrict__ A,
                                               const bf16* __restrict__ B,
                                               const float* __restrict__ bias,
                                               TC* __restrict__ C,
                                               int M, int N, int K,
                                               const float* __restrict__ resid,
                                               const float* __restrict__ gatep) {
    constexpr int LDR = 40;                 // padded LDS row (shorts), 80B: 16B-aligned, 2-way max
    __shared__ short As[128 * LDR];
    __shared__ short Bs[128 * LDR];
    int tid = threadIdx.x;
    int lane = tid & 63, wid = tid >> 6;

    // ---- XCD swizzle: each XCD owns a contiguous range of N-tile columns
    int gx = gridDim.x, gy = gridDim.y;
    int nwg = gx * gy;
    int bid = blockIdx.y * gx + blockIdx.x;         // dispatch-order index
    int cpx = nwg >> 3;
    int swz = (bid & 7) * cpx + (bid >> 3);
    int bx = swz / gy;                              // N-tile major within XCD chunk
    int by = swz - bx * gy;
    int m0 = by * 128, n0 = bx * 128;

    int wm = (wid >> 1) << 6, wn = (wid & 1) << 6;  // wave sub-tile origin

    // staging granule mapping: granule g -> row g>>2, col (g&3)*8 shorts
    int r0 = tid >> 2, c0 = (tid & 3) << 3;                    // granule tid
    int r1 = (tid + 256) >> 2, c1 = ((tid + 256) & 3) << 3;    // granule tid+256
    const bf16* Asrc0 = A + (size_t)(m0 + r0) * K + c0;
    const bf16* Asrc1 = A + (size_t)(m0 + r1) * K + c1;
    int nr0 = n0 + r0, nr1 = n0 + r1;
    const bf16* Bsrc0 = B + (size_t)nr0 * K + c0;
    const bf16* Bsrc1 = B + (size_t)nr1 * K + c1;
    bool bok0 = nr0 < N, bok1 = nr1 < N;

    f4v acc[4][4];
#pragma unroll
    for (int i = 0; i < 4; ++i)
#pragma unroll
        for (int j = 0; j < 4; ++j) acc[i][j] = (f4v){0.f, 0.f, 0.f, 0.f};

    const uint4 uz = make_uint4(0u, 0u, 0u, 0u);
    for (int k0 = 0; k0 < K; k0 += 32) {
        // global loads (independent of LDS) — issue before the barrier region
        uint4 a0 = *(const uint4*)(const void*)(Asrc0 + k0);
        uint4 a1 = *(const uint4*)(const void*)(Asrc1 + k0);
        uint4 b0 = bok0 ? *(const uint4*)(const void*)(Bsrc0 + k0) : uz;
        uint4 b1 = bok1 ? *(const uint4*)(const void*)(Bsrc1 + k0) : uz;
        __syncthreads();                    // previous iter's LDS reads complete
        *(uint4*)&As[r0 * LDR + c0] = a0;
        *(uint4*)&As[r1 * LDR + c1] = a1;
        *(uint4*)&Bs[r0 * LDR + c0] = b0;
        *(uint4*)&Bs[r1 * LDR + c1] = b1;
        __syncthreads();
        // ---- fragments + MFMA
        int row16 = lane & 15, kg = (lane >> 4) << 3;
        bf8v af[4], bfv[4];
#pragma unroll
        for (int fm = 0; fm < 4; ++fm)
            af[fm] = *(const bf8v*)&As[(wm + (fm << 4) + row16) * LDR + kg];
#pragma unroll
        for (int fn = 0; fn < 4; ++fn)
            bfv[fn] = *(const bf8v*)&Bs[(wn + (fn << 4) + row16) * LDR + kg];
#pragma unroll
        for (int fm = 0; fm < 4; ++fm)
#pragma unroll
            for (int fn = 0; fn < 4; ++fn)
                acc[fm][fn] = __builtin_amdgcn_mfma_f32_16x16x32_bf16(
                    af[fm], bfv[fn], acc[fm][fn], 0, 0, 0);
    }

    // ---- epilogue: C/D layout col = lane&15, row = (lane>>4)*4 + r
    float gate = (EPI == 1) ? *gatep : 0.f;
    int rbase = m0 + wm + ((lane >> 4) << 2);
#pragma unroll
    for (int fn = 0; fn < 4; ++fn) {
        int col = n0 + wn + (fn << 4) + (lane & 15);
        if (col >= N) continue;
        float bc = bias[col];
#pragma unroll
        for (int fm = 0; fm < 4; ++fm) {
#pragma unroll
            for (int r = 0; r < 4; ++r) {
                int row = rbase + (fm << 4) + r;
                float v = acc[fm][fn][r] + bc;
                if (EPI == 1)
                    v = resid[(size_t)row * N + col] + clampf(v, -100.f, 100.f) * gate;
                st1(&C[(size_t)row * N + col], v);
            }
        }
    }
}

// ---------------------------------------------------------------- save last 3 rows of x for next segment's conv halo
__global__ __launch_bounds__(256) void k_save_halo(const bf16* __restrict__ x,
                                                   bf16* __restrict__ dst) {
    int i = blockIdx.x * 256 + threadIdx.x;
    if (i < 3 * DINNER) dst[i] = x[(size_t)(SEG_T - 3) * DINNER + i];
}

// ---------------------------------------------------------------- depthwise causal conv (k=4) + SiLU, segment-local
__global__ __launch_bounds__(256) void k_conv_silu(const bf16* __restrict__ x,
                                                   const bf16* __restrict__ xh,
                                                   const float* __restrict__ cw,
                                                   const float* __restrict__ cb,
                                                   bf16* __restrict__ xc,
                                                   int l0) {
    int c = blockIdx.x * 256 + threadIdx.x;   // < DINNER
    int r = blockIdx.y;                       // 0..SEG_T-1
    int l = l0 + r;
    float acc = cb[c];
#pragma unroll
    for (int k = 0; k < 4; ++k) {
        int lp = l - 3 + k;
        if (lp < 0) continue;
        float v = (lp < l0) ? bf2f(xh[(size_t)(lp - l0 + 3) * DINNER + c])
                            : bf2f(x[(size_t)(lp - l0) * DINNER + c]);
        acc += cw[c * 4 + k] * v;
    }
    float sig = 1.f / (1.f + expf(-acc));
    xc[(size_t)r * DINNER + c] = f2bf(acc * sig);
}

// ---------------------------------------------------------------- per-(t,h): A value, 1/||B||, 1/||C|| (segment-local)
__global__ __launch_bounds__(256) void k_prep(const bf16* __restrict__ xp,
                                              const float* __restrict__ A_log,
                                              float* __restrict__ Aarr,
                                              float* __restrict__ invB,
                                              float* __restrict__ invC) {
    int wv = threadIdx.x >> 6, lane = threadIdx.x & 63;
    int idx = blockIdx.x * 4 + wv;            // t_local*24 + h, < SEG_T*24
    int t = idx / 24, h = idx - t * 24;
    const bf16* base = xp + (size_t)t * NPROJ + h * 129;
    float b = bf2f(base[1 + lane]), c = bf2f(base[65 + lane]);
    float sb = b * b, sc = c * c;
    for (int off = 32; off; off >>= 1) {
        sb += __shfl_xor(sb, off, 64);
        sc += __shfl_xor(sc, off, 64);
    }
    if (lane == 0) {
        invB[idx] = 1.f / fmaxf(sqrtf(sb), 1e-12f);
        invC[idx] = 1.f / fmaxf(sqrtf(sc), 1e-12f);
        float dt = clampf(bf2f(base[0]), -10.f, 10.f);
        float dts = clampf(log1pf(expf(dt)), 0.01f, 10.f);
        float A = clampf(A_log[h], -2.3f, -0.01f) * dts;
        Aarr[idx] = clampf(A, -20.f, -0.001f);
    }
}

// ---------------------------------------------------------------- chunk surprise (segment-local inputs, global cs)
__global__ __launch_bounds__(256) void k_surprise(const bf16* __restrict__ xp,
                                                  const bf16* __restrict__ xc,
                                                  const float* __restrict__ invB,
                                                  float* __restrict__ cs,
                                                  int b, int l0) {
    int g = blockIdx.x;                // 0..1535
    int h = g >> 6, nl = g & 63;
    int t0l = nl * 64;
    __shared__ float Bs[64][68];
    __shared__ float Xs[64][68];
    int tid = threadIdx.x, s = tid & 63, cw0 = tid >> 6;
    for (int it = 0; it < 16; ++it) {
        int c = cw0 + (it << 2);
        int t = t0l + c;
        Bs[c][s] = bf2f(xp[(size_t)t * NPROJ + h * 129 + 1 + s]) * invB[t * 24 + h];
        Xs[c][s] = bf2f(xc[(size_t)t * DINNER + h * 64 + s]);
    }
    __syncthreads();
    int s0 = (tid >> 4) << 2, d0 = (tid & 15) << 2;
    float acc[4][4] = {};
    for (int c = 0; c < 64; ++c) {
        const float4 b_ = *(const float4*)&Bs[c][s0];
        const float4 x_ = *(const float4*)&Xs[c][d0];
        const float br[4] = {b_.x, b_.y, b_.z, b_.w};
        const float xr[4] = {x_.x, x_.y, x_.z, x_.w};
#pragma unroll
        for (int r = 0; r < 4; ++r)
#pragma unroll
            for (int q = 0; q < 4; ++q) acc[r][q] += br[r] * xr[q];
    }
    float ss = 0.f;
#pragma unroll
    for (int r = 0; r < 4; ++r)
#pragma unroll
        for (int q = 0; q < 4; ++q) ss += acc[r][q] * acc[r][q];
    for (int off = 32; off; off >>= 1) ss += __shfl_xor(ss, off, 64);
    __shared__ float ws4[4];
    int lane = tid & 63, wv = tid >> 6;
    if (lane == 0) ws4[wv] = ss;
    __syncthreads();
    if (tid == 0)
        cs[(size_t)(b * 24 + h) * 128 + (l0 >> 6) + nl] =
            (ws4[0] + ws4[1] + ws4[2] + ws4[3]) * (1.f / 4096.f);
}

// ---------------------------------------------------------------- per-head EMA + alpha (global)
__global__ __launch_bounds__(256) void k_alpha(const float* __restrict__ cs,
                                               const float* __restrict__ ema0,
                                               const float* __restrict__ l2ab,
                                               const float* __restrict__ l2b,
                                               float* __restrict__ alpha) {
    int h = blockIdx.x, tid = threadIdx.x;
    int b = tid >> 7, n = tid & 127;
    int gi = (b * 24 + h) * 128 + n;
    float v = cs[gi];
    float s = v;
    for (int off = 32; off; off >>= 1) s += __shfl_xor(s, off, 64);
    __shared__ float ws4[4];
    int lane = tid & 63, wv = tid >> 6;
    if (lane == 0) ws4[wv] = s;
    __syncthreads();
    float total = ws4[0] + ws4[1] + ws4[2] + ws4[3];
    float ema = 0.99f * ema0[h] + 0.01f * (total * (1.f / 256.f));
    float ab = 1.f - exp2f(clampf(l2ab[h], -3.32f, -0.015f));
    float beta = exp2f(clampf(l2b[h], -2.f, 2.f));
    float nz = v / (ema + 1e-6f);
    float boost = fmaxf(tanhf(beta * nz), 0.f);
    alpha[gi] = clampf(ab + (1.f - ab) * boost, 0.01f, 0.999f);
}

// ---------------------------------------------------------------- intra-chunk: Y_intra = (L ∘ C B^T) X
__global__ __launch_bounds__(256) void k_intra(const bf16* __restrict__ xp,
                                               const bf16* __restrict__ xc,
                                               const float* __restrict__ invB,
                                               const float* __restrict__ invC,
                                               const float* __restrict__ Aarr,
                                               const float* __restrict__ alpha,
                                               bf16* __restrict__ ybuf,
                                               int b, int l0) {
    int g = blockIdx.x;
    int h = g >> 6, nl = g & 63;
    int t0l = nl * 64;
    float alp = alpha[(size_t)(b * 24 + h) * 128 + (l0 >> 6) + nl];
    __shared__ float Ct[64][68];   // [s][i]
    __shared__ float Bt[64][68];   // [s][j] -> later M^T[j][i]
    __shared__ float Xn[64][68];   // [c][d]
    __shared__ float Acs[64];
    int tid = threadIdx.x;
    if (tid < 64) {
        float a = Aarr[(size_t)(t0l + tid) * 24 + h] * (1.f - alp);
        for (int off = 1; off < 64; off <<= 1) {
            float u = __shfl_up(a, off, 64);
            if (tid >= off) a += u;
        }
        Acs[tid] = a;
    }
    int s = tid & 63, cw0 = tid >> 6;
    for (int it = 0; it < 16; ++it) {
        int c = cw0 + (it << 2);
        int t = t0l + c;
        const bf16* bp = xp + (size_t)t * NPROJ + h * 129;
        Bt[s][c] = bf2f(bp[1 + s]) * invB[t * 24 + h];
        Ct[s][c] = bf2f(bp[65 + s]) * invC[t * 24 + h];
        Xn[c][s] = bf2f(xc[(size_t)t * DINNER + h * 64 + s]);
    }
    __syncthreads();
    int i0 = (tid >> 4) << 2, j0 = (tid & 15) << 2;
    float cb[4][4] = {};
    for (int ss = 0; ss < 64; ++ss) {
        const float4 c_ = *(const float4*)&Ct[ss][i0];
        const float4 b_ = *(const float4*)&Bt[ss][j0];
        const float cr[4] = {c_.x, c_.y, c_.z, c_.w};
        const float br[4] = {b_.x, b_.y, b_.z, b_.w};
#pragma unroll
        for (int r = 0; r < 4; ++r)
#pragma unroll
            for (int q = 0; q < 4; ++q) cb[r][q] += cr[r] * br[q];
    }
    __syncthreads();
#pragma unroll
    for (int r = 0; r < 4; ++r) {
        float ai = Acs[i0 + r];
#pragma unroll
        for (int q = 0; q < 4; ++q) {
            int j = j0 + q;
            float m = (j <= i0 + r) ? expf(ai - Acs[j]) * cb[r][q] : 0.f;
            Bt[j][i0 + r] = m;
        }
    }
    __syncthreads();
    float y[4][4] = {};
    for (int jj = 0; jj < 64; ++jj) {
        const float4 m_ = *(const float4*)&Bt[jj][i0];
        const float4 x_ = *(const float4*)&Xn[jj][j0];
        const float mr[4] = {m_.x, m_.y, m_.z, m_.w};
        const float xr[4] = {x_.x, x_.y, x_.z, x_.w};
#pragma unroll
        for (int r = 0; r < 4; ++r)
#pragma unroll
            for (int q = 0; q < 4; ++q) y[r][q] += mr[r] * xr[q];
    }
#pragma unroll
    for (int r = 0; r < 4; ++r) {
        int t = t0l + i0 + r;
        st4(&ybuf[(size_t)t * DINNER + h * 64 + j0],
            make_float4(y[r][0], y[r][1], y[r][2], y[r][3]));
    }
}

// ---------------------------------------------------------------- h_chunk_final + decay_chunk
__global__ __launch_bounds__(256) void k_hchunk(const bf16* __restrict__ xp,
                                                const bf16* __restrict__ xc,
                                                const float* __restrict__ invB,
                                                const float* __restrict__ Aarr,
                                                const float* __restrict__ alpha,
                                                bf16* __restrict__ hf,
                                                float* __restrict__ dchunk,
                                                int b, int l0) {
    int g = blockIdx.x;
    int h = g >> 6, nl = g & 63;
    int t0l = nl * 64;
    size_t gidx = (size_t)(b * 24 + h) * 128 + (l0 >> 6) + nl;
    float alp = alpha[gidx];
    __shared__ float Bn[64][68];
    __shared__ float Xn[64][68];
    __shared__ float dte[64];
    int tid = threadIdx.x;
    if (tid < 64) {
        float a = Aarr[(size_t)(t0l + tid) * 24 + h] * (1.f - alp);
        for (int off = 1; off < 64; off <<= 1) {
            float u = __shfl_up(a, off, 64);
            if (tid >= off) a += u;
        }
        float total = __shfl(a, 63, 64);
        dte[tid] = expf(total - a);
        if (tid == 0) dchunk[gidx] = expf(total);
    }
    int s = tid & 63, cw0 = tid >> 6;
    for (int it = 0; it < 16; ++it) {
        int c = cw0 + (it << 2);
        int t = t0l + c;
        Bn[c][s] = bf2f(xp[(size_t)t * NPROJ + h * 129 + 1 + s]) * invB[t * 24 + h];
        Xn[c][s] = bf2f(xc[(size_t)t * DINNER + h * 64 + s]);
    }
    __syncthreads();
    int s0 = (tid >> 4) << 2, d0 = (tid & 15) << 2;
    float acc[4][4] = {};
    for (int c = 0; c < 64; ++c) {
        float w = dte[c];
        const float4 b_ = *(const float4*)&Bn[c][s0];
        const float4 x_ = *(const float4*)&Xn[c][d0];
        const float br[4] = {w * b_.x, w * b_.y, w * b_.z, w * b_.w};
        const float xr[4] = {x_.x, x_.y, x_.z, x_.w};
#pragma unroll
        for (int r = 0; r < 4; ++r)
#pragma unroll
            for (int q = 0; q < 4; ++q) acc[r][q] += br[r] * xr[q];
    }
#pragma unroll
    for (int r = 0; r < 4; ++r) {
        st4(&hf[(size_t)(h * SEG_CH + nl) * 4096 + (size_t)(s0 + r) * 64 + d0],
            make_float4(acc[r][0], acc[r][1], acc[r][2], acc[r][3]));
    }
}

// ---------------------------------------------------------------- chunk scan within segment, carry across segments
__global__ __launch_bounds__(256) void k_scan(bf16* __restrict__ hf,
                                              const float* __restrict__ dchunk,
                                              float* __restrict__ carry,
                                              int b, int l0) {
    int h = blockIdx.x >> 4;                        // 0..23
    int e = ((blockIdx.x & 15) << 8) + threadIdx.x; // 0..4095
    int bh = b * 24 + h;
    float c = (l0 == 0) ? 0.f : carry[(size_t)bh * 4096 + e];
    for (int nl = 0; nl < SEG_CH; ++nl) {
        float dc = dchunk[(size_t)bh * 128 + (l0 >> 6) + nl];
        size_t a = (size_t)(h * SEG_CH + nl) * 4096 + e;
        float v = bf2f(hf[a]);
        hf[a] = f2bf(c);
        c = dc * c + v;
    }
    carry[(size_t)bh * 4096 + e] = c;
}

// ---------------------------------------------------------------- Y_inter + gate (in place on ybuf)
__global__ __launch_bounds__(256) void k_inter(const bf16* __restrict__ xp,
                                               const float* __restrict__ invC,
                                               const float* __restrict__ Aarr,
                                               const float* __restrict__ alpha,
                                               const bf16* __restrict__ hf,
                                               const bf16* __restrict__ zbuf,
                                               bf16* __restrict__ ybuf,
                                               int b, int l0) {
    int g = blockIdx.x;
    int h = g >> 6, nl = g & 63;
    int t0l = nl * 64;
    float alp = alpha[(size_t)(b * 24 + h) * 128 + (l0 >> 6) + nl];
    __shared__ float Ct[64][68];   // [s][i]
    __shared__ float Hs[64][68];   // [s][d]
    __shared__ float dfs[64];
    int tid = threadIdx.x;
    if (tid < 64) {
        float a = Aarr[(size_t)(t0l + tid) * 24 + h] * (1.f - alp);
        for (int off = 1; off < 64; off <<= 1) {
            float u = __shfl_up(a, off, 64);
            if (tid >= off) a += u;
        }
        dfs[tid] = expf(a);
    }
    int s = tid & 63, cw0 = tid >> 6;
    for (int it = 0; it < 16; ++it) {
        int row = cw0 + (it << 2);
        int t = t0l + row;
        Ct[s][row] = bf2f(xp[(size_t)t * NPROJ + h * 129 + 65 + s]) * invC[t * 24 + h];
        Hs[row][s] = bf2f(hf[(size_t)(h * SEG_CH + nl) * 4096 + (size_t)row * 64 + s]);
    }
    __syncthreads();
    int i0 = (tid >> 4) << 2, d0 = (tid & 15) << 2;
    float acc[4][4] = {};
    for (int ss = 0; ss < 64; ++ss) {
        const float4 c_ = *(const float4*)&Ct[ss][i0];
        const float4 h_ = *(const float4*)&Hs[ss][d0];
        const float cr[4] = {c_.x, c_.y, c_.z, c_.w};
        const float hr[4] = {h_.x, h_.y, h_.z, h_.w};
#pragma unroll
        for (int r = 0; r < 4; ++r)
#pragma unroll
            for (int q = 0; q < 4; ++q) acc[r][q] += cr[r] * hr[q];
    }
#pragma unroll
    for (int r = 0; r < 4; ++r) {
        int t = t0l + i0 + r;
        float df = dfs[i0 + r];
        size_t yoff = (size_t)t * DINNER + h * 64 + d0;
#pragma unroll
        for (int q = 0; q < 4; ++q) {
            float Y = clampf(bf2f(ybuf[yoff + q]) + df * acc[r][q], -100.f, 100.f);
            float zz = bf2f(zbuf[yoff + q]);
            ybuf[yoff + q] = f2bf(Y / (1.f + expf(-zz)));
        }
    }
}

// ---------------------------------------------------------------- launch
extern "C" void kernel_launch(void* const* d_in, const int* in_sizes, int n_in,
                              void* d_out, int out_size, void* d_ws, size_t ws_size,
                              hipStream_t stream) {
    const float* hs     = (const float*)d_in[0];
    const float* norm_w = (const float*)d_in[1];
    const float* w1     = (const float*)d_in[2];
    const float* b1     = (const float*)d_in[3];
    const float* cw     = (const float*)d_in[4];
    const float* cbias  = (const float*)d_in[5];
    const float* w2     = (const float*)d_in[6];
    const float* b2     = (const float*)d_in[7];
    const float* A_log  = (const float*)d_in[8];
    const float* l2ab   = (const float*)d_in[9];
    const float* l2b    = (const float*)d_in[10];
    const float* ema0   = (const float*)d_in[11];
    const float* w3     = (const float*)d_in[12];
    const float* b3     = (const float*)d_in[13];
    const float* rg     = (const float*)d_in[14];
    float* out = (float*)d_out;

    // ---- workspace layout (~84 MiB)
    char* base = (char*)d_ws;
    size_t off = 0;
    auto alloc = [&](size_t bytes) -> void* {
        void* p = base + off;
        off += (bytes + 255) & ~(size_t)255;
        return p;
    };
    bf16* w1bf  = (bf16*)alloc((size_t)2 * DINNER * DMODEL * 2);
    bf16* w2bf  = (bf16*)alloc((size_t)NPROJ * DINNER * 2);
    bf16* w3bf  = (bf16*)alloc((size_t)DMODEL * DINNER * 2);
    bf16* xn    = (bf16*)alloc((size_t)SEG_T * DMODEL * 2);
    bf16* zbuf  = (bf16*)alloc((size_t)SEG_T * DINNER * 2);
    bf16* ybuf  = (bf16*)alloc((size_t)SEG_T * DINNER * 2);   // phase-1: xbuf alias
    bf16* xp    = (bf16*)alloc((size_t)SEG_T * NPROJ * 2);
    bf16* hf    = (bf16*)alloc((size_t)NHEADS * SEG_CH * 4096 * 2);
    bf16* xhalo = (bf16*)alloc((size_t)2 * 3 * DINNER * 2);
    float* Aarr = (float*)alloc((size_t)SEG_T * 24 * 4);
    float* invB = (float*)alloc((size_t)SEG_T * 24 * 4);
    float* invC = (float*)alloc((size_t)SEG_T * 24 * 4);
    float* cs   = (float*)alloc((size_t)6144 * 4);
    float* alp  = (float*)alloc((size_t)6144 * 4);
    float* dch  = (float*)alloc((size_t)6144 * 4);
    float* carry= (float*)alloc((size_t)48 * 4096 * 4);
    bf16* xbuf  = ybuf;                    // phase-1 pre-conv x
    bf16* xc_all = (bf16*)d_out;           // xc for ALL tokens lives in d_out (exact fit)

    // ---- weights -> bf16 (once per launch)
    {
        int n1 = 2 * DINNER * DMODEL / 4, n2 = NPROJ * DINNER / 4, n3 = DMODEL * DINNER / 4;
        k_cvt<<<(n1 + 255) / 256, 256, 0, stream>>>(w1, w1bf, n1);
        k_cvt<<<(n2 + 255) / 256, 256, 0, stream>>>(w2, w2bf, n2);
        k_cvt<<<(n3 + 255) / 256, 256, 0, stream>>>(w3, w3bf, n3);
    }

    const dim3 gX(DINNER / 128, SEG_T / 128);            // 12 x 32 = 384
    const dim3 gP((NPROJ + 127) / 128, SEG_T / 128);     // 25 x 32 = 800
    const dim3 gO(DMODEL / 128, SEG_T / 128);            // 6 x 32 = 192

    // ---------------- phase 1: front-end + surprise; xc cached into d_out
    for (int s = 0; s < NSEG; ++s) {
        size_t t0 = (size_t)s * SEG_T;
        int l0 = (int)(t0 & (L_SEQ - 1));
        int b  = (int)(t0 >> 13);
        const float* hseg = hs + t0 * DMODEL;
        bf16* xc = xc_all + t0 * DINNER;
        k_rmsnorm<<<SEG_T, 256, 0, stream>>>(hseg, norm_w, xn);
        k_mgemm<bf16, 0><<<gX, 256, 0, stream>>>(xn, w1bf, b1, xbuf,
                                                 SEG_T, DINNER, DMODEL, nullptr, nullptr);
        k_save_halo<<<18, 256, 0, stream>>>(xbuf, xhalo + (size_t)((s + 1) & 1) * 3 * DINNER);
        k_conv_silu<<<dim3(DINNER / 256, SEG_T), 256, 0, stream>>>(
            xbuf, xhalo + (size_t)(s & 1) * 3 * DINNER, cw, cbias, xc, l0);
        k_mgemm<bf16, 0><<<gP, 256, 0, stream>>>(xc, w2bf, b2, xp,
                                                 SEG_T, NPROJ, DINNER, nullptr, nullptr);
        k_prep<<<SEG_T * 24 / 4, 256, 0, stream>>>(xp, A_log, Aarr, invB, invC);
        k_surprise<<<NHEADS * SEG_CH, 256, 0, stream>>>(xp, xc, invB, cs, b, l0);
    }
    k_alpha<<<24, 256, 0, stream>>>(cs, ema0, l2ab, l2b, alp);

    // ---------------- phase 2: SSM + output per segment (xc reused from d_out)
    for (int s = 0; s < NSEG; ++s) {
        size_t t0 = (size_t)s * SEG_T;
        int l0 = (int)(t0 & (L_SEQ - 1));
        int b  = (int)(t0 >> 13);
        const float* hseg = hs + t0 * DMODEL;
        bf16* xc = xc_all + t0 * DINNER;
        k_rmsnorm<<<SEG_T, 256, 0, stream>>>(hseg, norm_w, xn);
        k_mgemm<bf16, 0><<<gX, 256, 0, stream>>>(xn, w1bf + (size_t)DINNER * DMODEL,
                                                 b1 + DINNER, zbuf,
                                                 SEG_T, DINNER, DMODEL, nullptr, nullptr);
        k_mgemm<bf16, 0><<<gP, 256, 0, stream>>>(xc, w2bf, b2, xp,
                                                 SEG_T, NPROJ, DINNER, nullptr, nullptr);
        k_prep<<<SEG_T * 24 / 4, 256, 0, stream>>>(xp, A_log, Aarr, invB, invC);
        k_intra<<<NHEADS * SEG_CH, 256, 0, stream>>>(xp, xc, invB, invC, Aarr, alp, ybuf, b, l0);
        k_hchunk<<<NHEADS * SEG_CH, 256, 0, stream>>>(xp, xc, invB, Aarr, alp, hf, dch, b, l0);
        k_scan<<<384, 256, 0, stream>>>(hf, dch, carry, b, l0);
        k_inter<<<NHEADS * SEG_CH, 256, 0, stream>>>(xp, invC, Aarr, alp, hf, zbuf, ybuf, b, l0);
        // overwrites this segment's (now dead) xc region of d_out
        k_mgemm<float, 1><<<gO, 256, 0, stream>>>(ybuf, w3bf, b3, out + t0 * DMODEL,
                                                  SEG_T, DMODEL, DINNER, hseg, rg);
    }
}

// Round 6
// 1349.506 us; speedup vs baseline: 5.9214x; 1.3982x over previous
//
#include <hip/hip_runtime.h>
#include <hip/hip_bf16.h>
#include <cstdint>
#include <cstddef>

#define L_SEQ   8192
#define DMODEL  768
#define NHEADS  24
#define DINNER  1536
#define NPROJ   3096      /* 24 * 129 */
#define NTOK    16384
#define SEG_T   4096      /* tokens per segment */
#define NSEG    4
#define SEG_CH  64        /* chunks per segment */
#define RMS_EPS 1.1920929e-07f

typedef __hip_bfloat16 bf16;
typedef __attribute__((ext_vector_type(8))) short bf8v;
typedef __attribute__((ext_vector_type(4))) float f4v;

__device__ __forceinline__ float clampf(float x, float lo, float hi) {
    return fminf(fmaxf(x, lo), hi);
}
__device__ __forceinline__ float bf2f(bf16 v) { return __bfloat162float(v); }
__device__ __forceinline__ bf16  f2bf(float v) { return __float2bfloat16(v); }
__device__ __forceinline__ void st1(float* p, float v) { *p = v; }
__device__ __forceinline__ void st1(bf16* p, float v) { *p = f2bf(v); }
__device__ __forceinline__ void st4(float* p, float4 v) { *(float4*)p = v; }
__device__ __forceinline__ void st4(bf16* p, float4 v) {
    p[0] = f2bf(v.x); p[1] = f2bf(v.y); p[2] = f2bf(v.z); p[3] = f2bf(v.w);
}

// ---------------------------------------------------------------- f32 -> bf16 weight conversion
__global__ __launch_bounds__(256) void k_cvt(const float* __restrict__ s,
                                             bf16* __restrict__ d, int n4) {
    int i = blockIdx.x * 256 + threadIdx.x;
    if (i < n4) {
        float4 v = *(const float4*)&s[i * 4];
        st4(&d[i * 4], v);
    }
}

// ---------------------------------------------------------------- RMSNorm (f32 in, bf16 out)
__global__ __launch_bounds__(256) void k_rmsnorm(const float* __restrict__ hs,
                                                 const float* __restrict__ w,
                                                 bf16* __restrict__ xn) {
    int t = blockIdx.x;
    const float* p = hs + (size_t)t * DMODEL;
    float s = 0.f;
    for (int i = threadIdx.x; i < DMODEL; i += 256) { float v = p[i]; s += v * v; }
    for (int off = 32; off; off >>= 1) s += __shfl_xor(s, off, 64);
    __shared__ float ws4[4];
    int lane = threadIdx.x & 63, wv = threadIdx.x >> 6;
    if (lane == 0) ws4[wv] = s;
    __syncthreads();
    s = ws4[0] + ws4[1] + ws4[2] + ws4[3];
    float r = 1.0f / sqrtf(s * (1.0f / DMODEL) + RMS_EPS);
    bf16* o = xn + (size_t)t * DMODEL;
    for (int i = threadIdx.x; i < DMODEL; i += 256) o[i] = f2bf(p[i] * r * w[i]);
}

// ---------------------------------------------------------------- MFMA GEMM  C[M,N] = A[M,K] @ B[N,K]^T + bias
// 128x128 tile, BK=32, 4 waves, register-prefetch pipeline, XCD swizzle.
template <typename TC, int EPI>
__global__ __launch_bounds__(256) void k_mgemm(const bf16* __restrict__ A,
                                               const bf16* __restrict__ B,
                                               const float* __restrict__ bias,
                                               TC* __restrict__ C,
                                               int M, int N, int K,
                                               const float* __restrict__ resid,
                                               const float* __restrict__ gatep) {
    constexpr int LDR = 40;
    __shared__ short As[128 * LDR];
    __shared__ short Bs[128 * LDR];
    int tid = threadIdx.x;
    int lane = tid & 63, wid = tid >> 6;

    int gx = gridDim.x, gy = gridDim.y;
    int nwg = gx * gy;
    int bid = blockIdx.y * gx + blockIdx.x;
    int cpx = nwg >> 3;
    int swz = (bid & 7) * cpx + (bid >> 3);
    int bx = swz / gy;
    int by = swz - bx * gy;
    int m0 = by * 128, n0 = bx * 128;

    int wm = (wid >> 1) << 6, wn = (wid & 1) << 6;

    int r0 = tid >> 2, c0 = (tid & 3) << 3;
    int r1 = (tid + 256) >> 2, c1 = ((tid + 256) & 3) << 3;
    const bf16* Asrc0 = A + (size_t)(m0 + r0) * K + c0;
    const bf16* Asrc1 = A + (size_t)(m0 + r1) * K + c1;
    int nr0 = n0 + r0, nr1 = n0 + r1;
    const bf16* Bsrc0 = B + (size_t)nr0 * K + c0;
    const bf16* Bsrc1 = B + (size_t)nr1 * K + c1;
    bool bok0 = nr0 < N, bok1 = nr1 < N;

    f4v acc[4][4];
#pragma unroll
    for (int i = 0; i < 4; ++i)
#pragma unroll
        for (int j = 0; j < 4; ++j) acc[i][j] = (f4v){0.f, 0.f, 0.f, 0.f};

    const uint4 uz = make_uint4(0u, 0u, 0u, 0u);
    // prologue loads (k=0)
    uint4 a0 = *(const uint4*)(const void*)Asrc0;
    uint4 a1 = *(const uint4*)(const void*)Asrc1;
    uint4 b0 = bok0 ? *(const uint4*)(const void*)Bsrc0 : uz;
    uint4 b1 = bok1 ? *(const uint4*)(const void*)Bsrc1 : uz;

    for (int k0 = 0; k0 < K; k0 += 32) {
        __syncthreads();
        *(uint4*)&As[r0 * LDR + c0] = a0;
        *(uint4*)&As[r1 * LDR + c1] = a1;
        *(uint4*)&Bs[r0 * LDR + c0] = b0;
        *(uint4*)&Bs[r1 * LDR + c1] = b1;
        __syncthreads();
        // prefetch next tile (clamped redundant load on the last iter)
        int kn = (k0 + 32 < K) ? k0 + 32 : k0;
        a0 = *(const uint4*)(const void*)(Asrc0 + kn);
        a1 = *(const uint4*)(const void*)(Asrc1 + kn);
        b0 = bok0 ? *(const uint4*)(const void*)(Bsrc0 + kn) : uz;
        b1 = bok1 ? *(const uint4*)(const void*)(Bsrc1 + kn) : uz;
        // fragments + MFMA (overlaps with in-flight prefetch)
        int row16 = lane & 15, kg = (lane >> 4) << 3;
        bf8v af[4], bfv[4];
#pragma unroll
        for (int fm = 0; fm < 4; ++fm)
            af[fm] = *(const bf8v*)&As[(wm + (fm << 4) + row16) * LDR + kg];
#pragma unroll
        for (int fn = 0; fn < 4; ++fn)
            bfv[fn] = *(const bf8v*)&Bs[(wn + (fn << 4) + row16) * LDR + kg];
#pragma unroll
        for (int fm = 0; fm < 4; ++fm)
#pragma unroll
            for (int fn = 0; fn < 4; ++fn)
                acc[fm][fn] = __builtin_amdgcn_mfma_f32_16x16x32_bf16(
                    af[fm], bfv[fn], acc[fm][fn], 0, 0, 0);
    }

    float gate = (EPI == 1) ? *gatep : 0.f;
    int rbase = m0 + wm + ((lane >> 4) << 2);
#pragma unroll
    for (int fn = 0; fn < 4; ++fn) {
        int col = n0 + wn + (fn << 4) + (lane & 15);
        if (col >= N) continue;
        float bc = bias[col];
#pragma unroll
        for (int fm = 0; fm < 4; ++fm) {
#pragma unroll
            for (int r = 0; r < 4; ++r) {
                int row = rbase + (fm << 4) + r;
                float v = acc[fm][fn][r] + bc;
                if (EPI == 1)
                    v = resid[(size_t)row * N + col] + clampf(v, -100.f, 100.f) * gate;
                st1(&C[(size_t)row * N + col], v);
            }
        }
    }
}

// ---------------------------------------------------------------- save last 3 rows of x for next segment's conv halo
__global__ __launch_bounds__(256) void k_save_halo(const bf16* __restrict__ x,
                                                   bf16* __restrict__ dst) {
    int i = blockIdx.x * 256 + threadIdx.x;
    if (i < 3 * DINNER) dst[i] = x[(size_t)(SEG_T - 3) * DINNER + i];
}

// ---------------------------------------------------------------- depthwise causal conv (k=4) + SiLU
__global__ __launch_bounds__(256) void k_conv_silu(const bf16* __restrict__ x,
                                                   const bf16* __restrict__ xh,
                                                   const float* __restrict__ cw,
                                                   const float* __restrict__ cb,
                                                   bf16* __restrict__ xc,
                                                   int l0) {
    int c = blockIdx.x * 256 + threadIdx.x;
    int r = blockIdx.y;
    int l = l0 + r;
    float acc = cb[c];
#pragma unroll
    for (int k = 0; k < 4; ++k) {
        int lp = l - 3 + k;
        if (lp < 0) continue;
        float v = (lp < l0) ? bf2f(xh[(size_t)(lp - l0 + 3) * DINNER + c])
                            : bf2f(x[(size_t)(lp - l0) * DINNER + c]);
        acc += cw[c * 4 + k] * v;
    }
    float sig = 1.f / (1.f + expf(-acc));
    xc[(size_t)r * DINNER + c] = f2bf(acc * sig);
}

// ---------------------------------------------------------------- per-(t,h): A value, 1/||B||, 1/||C||
__global__ __launch_bounds__(256) void k_prep(const bf16* __restrict__ xp,
                                              const float* __restrict__ A_log,
                                              float* __restrict__ Aarr,
                                              float* __restrict__ invB,
                                              float* __restrict__ invC) {
    int wv = threadIdx.x >> 6, lane = threadIdx.x & 63;
    int idx = blockIdx.x * 4 + wv;
    int t = idx / 24, h = idx - t * 24;
    const bf16* base = xp + (size_t)t * NPROJ + h * 129;
    float b = bf2f(base[1 + lane]), c = bf2f(base[65 + lane]);
    float sb = b * b, sc = c * c;
    for (int off = 32; off; off >>= 1) {
        sb += __shfl_xor(sb, off, 64);
        sc += __shfl_xor(sc, off, 64);
    }
    if (lane == 0) {
        invB[idx] = 1.f / fmaxf(sqrtf(sb), 1e-12f);
        invC[idx] = 1.f / fmaxf(sqrtf(sc), 1e-12f);
        float dt = clampf(bf2f(base[0]), -10.f, 10.f);
        float dts = clampf(log1pf(expf(dt)), 0.01f, 10.f);
        float A = clampf(A_log[h], -2.3f, -0.01f) * dts;
        Aarr[idx] = clampf(A, -20.f, -0.001f);
    }
}

// ---------------------------------------------------------------- chunk surprise (body shared; two index wrappers)
__device__ __forceinline__ void surprise_body(const bf16* xp, const bf16* xc,
                                              const float* invB, float* cs,
                                              int t0, int h, size_t cs_idx) {
    __shared__ float Bs[64][68];
    __shared__ float Xs[64][68];
    int tid = threadIdx.x, s = tid & 63, cw0 = tid >> 6;
    for (int it = 0; it < 16; ++it) {
        int c = cw0 + (it << 2);
        int t = t0 + c;
        Bs[c][s] = bf2f(xp[(size_t)t * NPROJ + h * 129 + 1 + s]) * invB[t * 24 + h];
        Xs[c][s] = bf2f(xc[(size_t)t * DINNER + h * 64 + s]);
    }
    __syncthreads();
    int s0 = (tid >> 4) << 2, d0 = (tid & 15) << 2;
    float acc[4][4] = {};
    for (int c = 0; c < 64; ++c) {
        const float4 b_ = *(const float4*)&Bs[c][s0];
        const float4 x_ = *(const float4*)&Xs[c][d0];
        const float br[4] = {b_.x, b_.y, b_.z, b_.w};
        const float xr[4] = {x_.x, x_.y, x_.z, x_.w};
#pragma unroll
        for (int r = 0; r < 4; ++r)
#pragma unroll
            for (int q = 0; q < 4; ++q) acc[r][q] += br[r] * xr[q];
    }
    float ss = 0.f;
#pragma unroll
    for (int r = 0; r < 4; ++r)
#pragma unroll
        for (int q = 0; q < 4; ++q) ss += acc[r][q] * acc[r][q];
    for (int off = 32; off; off >>= 1) ss += __shfl_xor(ss, off, 64);
    __shared__ float ws4[4];
    int lane = tid & 63, wv = tid >> 6;
    if (lane == 0) ws4[wv] = ss;
    __syncthreads();
    if (tid == 0) cs[cs_idx] = (ws4[0] + ws4[1] + ws4[2] + ws4[3]) * (1.f / 4096.f);
}

__global__ __launch_bounds__(256) void k_surprise(const bf16* __restrict__ xp,
                                                  const bf16* __restrict__ xc,
                                                  const float* __restrict__ invB,
                                                  float* __restrict__ cs,
                                                  int b, int l0) {
    int g = blockIdx.x;
    int h = g >> 6, nl = g & 63;
    surprise_body(xp, xc, invB, cs, nl * 64, h,
                  (size_t)(b * 24 + h) * 128 + (l0 >> 6) + nl);
}

// big path: one launch over all 6144 chunks; xp/xc/invB are full-NTOK arrays
__global__ __launch_bounds__(256) void k_surprise_all(const bf16* __restrict__ xp,
                                                      const bf16* __restrict__ xc,
                                                      const float* __restrict__ invB,
                                                      float* __restrict__ cs) {
    int g = blockIdx.x;                 // 0..6143
    int cg = g / 24, h = g - cg * 24;   // cg: global chunk 0..255
    int b = cg >> 7, nl = cg & 127;
    surprise_body(xp, xc, invB, cs, cg * 64, h, (size_t)(b * 24 + h) * 128 + nl);
}

// ---------------------------------------------------------------- per-head EMA + alpha
__global__ __launch_bounds__(256) void k_alpha(const float* __restrict__ cs,
                                               const float* __restrict__ ema0,
                                               const float* __restrict__ l2ab,
                                               const float* __restrict__ l2b,
                                               float* __restrict__ alpha) {
    int h = blockIdx.x, tid = threadIdx.x;
    int b = tid >> 7, n = tid & 127;
    int gi = (b * 24 + h) * 128 + n;
    float v = cs[gi];
    float s = v;
    for (int off = 32; off; off >>= 1) s += __shfl_xor(s, off, 64);
    __shared__ float ws4[4];
    int lane = tid & 63, wv = tid >> 6;
    if (lane == 0) ws4[wv] = s;
    __syncthreads();
    float total = ws4[0] + ws4[1] + ws4[2] + ws4[3];
    float ema = 0.99f * ema0[h] + 0.01f * (total * (1.f / 256.f));
    float ab = 1.f - exp2f(clampf(l2ab[h], -3.32f, -0.015f));
    float beta = exp2f(clampf(l2b[h], -2.f, 2.f));
    float nz = v / (ema + 1e-6f);
    float boost = fmaxf(tanhf(beta * nz), 0.f);
    alpha[gi] = clampf(ab + (1.f - ab) * boost, 0.01f, 0.999f);
}

// ---------------------------------------------------------------- intra-chunk: Y_intra = (L ∘ C B^T) X
__global__ __launch_bounds__(256) void k_intra(const bf16* __restrict__ xp,
                                               const bf16* __restrict__ xc,
                                               const float* __restrict__ invB,
                                               const float* __restrict__ invC,
                                               const float* __restrict__ Aarr,
                                               const float* __restrict__ alpha,
                                               bf16* __restrict__ ybuf,
                                               int b, int l0) {
    int g = blockIdx.x;
    int h = g >> 6, nl = g & 63;
    int t0l = nl * 64;
    float alp = alpha[(size_t)(b * 24 + h) * 128 + (l0 >> 6) + nl];
    __shared__ float Ct[64][68];
    __shared__ float Bt[64][68];
    __shared__ float Xn[64][68];
    __shared__ float Acs[64];
    int tid = threadIdx.x;
    if (tid < 64) {
        float a = Aarr[(size_t)(t0l + tid) * 24 + h] * (1.f - alp);
        for (int off = 1; off < 64; off <<= 1) {
            float u = __shfl_up(a, off, 64);
            if (tid >= off) a += u;
        }
        Acs[tid] = a;
    }
    int s = tid & 63, cw0 = tid >> 6;
    for (int it = 0; it < 16; ++it) {
        int c = cw0 + (it << 2);
        int t = t0l + c;
        const bf16* bp = xp + (size_t)t * NPROJ + h * 129;
        Bt[s][c] = bf2f(bp[1 + s]) * invB[t * 24 + h];
        Ct[s][c] = bf2f(bp[65 + s]) * invC[t * 24 + h];
        Xn[c][s] = bf2f(xc[(size_t)t * DINNER + h * 64 + s]);
    }
    __syncthreads();
    int i0 = (tid >> 4) << 2, j0 = (tid & 15) << 2;
    float cb[4][4] = {};
    for (int ss = 0; ss < 64; ++ss) {
        const float4 c_ = *(const float4*)&Ct[ss][i0];
        const float4 b_ = *(const float4*)&Bt[ss][j0];
        const float cr[4] = {c_.x, c_.y, c_.z, c_.w};
        const float br[4] = {b_.x, b_.y, b_.z, b_.w};
#pragma unroll
        for (int r = 0; r < 4; ++r)
#pragma unroll
            for (int q = 0; q < 4; ++q) cb[r][q] += cr[r] * br[q];
    }
    __syncthreads();
#pragma unroll
    for (int r = 0; r < 4; ++r) {
        float ai = Acs[i0 + r];
#pragma unroll
        for (int q = 0; q < 4; ++q) {
            int j = j0 + q;
            float m = (j <= i0 + r) ? expf(ai - Acs[j]) * cb[r][q] : 0.f;
            Bt[j][i0 + r] = m;
        }
    }
    __syncthreads();
    float y[4][4] = {};
    for (int jj = 0; jj < 64; ++jj) {
        const float4 m_ = *(const float4*)&Bt[jj][i0];
        const float4 x_ = *(const float4*)&Xn[jj][j0];
        const float mr[4] = {m_.x, m_.y, m_.z, m_.w};
        const float xr[4] = {x_.x, x_.y, x_.z, x_.w};
#pragma unroll
        for (int r = 0; r < 4; ++r)
#pragma unroll
            for (int q = 0; q < 4; ++q) y[r][q] += mr[r] * xr[q];
    }
#pragma unroll
    for (int r = 0; r < 4; ++r) {
        int t = t0l + i0 + r;
        st4(&ybuf[(size_t)t * DINNER + h * 64 + j0],
            make_float4(y[r][0], y[r][1], y[r][2], y[r][3]));
    }
}

// ---------------------------------------------------------------- h_chunk_final + decay_chunk
__global__ __launch_bounds__(256) void k_hchunk(const bf16* __restrict__ xp,
                                                const bf16* __restrict__ xc,
                                                const float* __restrict__ invB,
                                                const float* __restrict__ Aarr,
                                                const float* __restrict__ alpha,
                                                bf16* __restrict__ hf,
                                                float* __restrict__ dchunk,
                                                int b, int l0) {
    int g = blockIdx.x;
    int h = g >> 6, nl = g & 63;
    int t0l = nl * 64;
    size_t gidx = (size_t)(b * 24 + h) * 128 + (l0 >> 6) + nl;
    float alp = alpha[gidx];
    __shared__ float Bn[64][68];
    __shared__ float Xn[64][68];
    __shared__ float dte[64];
    int tid = threadIdx.x;
    if (tid < 64) {
        float a = Aarr[(size_t)(t0l + tid) * 24 + h] * (1.f - alp);
        for (int off = 1; off < 64; off <<= 1) {
            float u = __shfl_up(a, off, 64);
            if (tid >= off) a += u;
        }
        float total = __shfl(a, 63, 64);
        dte[tid] = expf(total - a);
        if (tid == 0) dchunk[gidx] = expf(total);
    }
    int s = tid & 63, cw0 = tid >> 6;
    for (int it = 0; it < 16; ++it) {
        int c = cw0 + (it << 2);
        int t = t0l + c;
        Bn[c][s] = bf2f(xp[(size_t)t * NPROJ + h * 129 + 1 + s]) * invB[t * 24 + h];
        Xn[c][s] = bf2f(xc[(size_t)t * DINNER + h * 64 + s]);
    }
    __syncthreads();
    int s0 = (tid >> 4) << 2, d0 = (tid & 15) << 2;
    float acc[4][4] = {};
    for (int c = 0; c < 64; ++c) {
        float w = dte[c];
        const float4 b_ = *(const float4*)&Bn[c][s0];
        const float4 x_ = *(const float4*)&Xn[c][d0];
        const float br[4] = {w * b_.x, w * b_.y, w * b_.z, w * b_.w};
        const float xr[4] = {x_.x, x_.y, x_.z, x_.w};
#pragma unroll
        for (int r = 0; r < 4; ++r)
#pragma unroll
            for (int q = 0; q < 4; ++q) acc[r][q] += br[r] * xr[q];
    }
#pragma unroll
    for (int r = 0; r < 4; ++r) {
        st4(&hf[(size_t)(h * SEG_CH + nl) * 4096 + (size_t)(s0 + r) * 64 + d0],
            make_float4(acc[r][0], acc[r][1], acc[r][2], acc[r][3]));
    }
}

// ---------------------------------------------------------------- chunk scan (prefetched)
__global__ __launch_bounds__(256) void k_scan(bf16* __restrict__ hf,
                                              const float* __restrict__ dchunk,
                                              float* __restrict__ carry,
                                              int b, int l0) {
    int h = blockIdx.x >> 4;
    int e = ((blockIdx.x & 15) << 8) + threadIdx.x;
    int bh = b * 24 + h;
    float c = (l0 == 0) ? 0.f : carry[(size_t)bh * 4096 + e];
    size_t a = (size_t)h * SEG_CH * 4096 + e;
    float v = bf2f(hf[a]);
    const float* dcp = dchunk + (size_t)bh * 128 + (l0 >> 6);
    for (int nl = 0; nl < SEG_CH; ++nl) {
        float dc = dcp[nl];
        float vn = (nl + 1 < SEG_CH) ? bf2f(hf[a + 4096]) : 0.f;  // prefetch next
        hf[a] = f2bf(c);
        c = dc * c + v;
        v = vn;
        a += 4096;
    }
    carry[(size_t)bh * 4096 + e] = c;
}

// ---------------------------------------------------------------- Y_inter + gate (in place on ybuf)
__global__ __launch_bounds__(256) void k_inter(const bf16* __restrict__ xp,
                                               const float* __restrict__ invC,
                                               const float* __restrict__ Aarr,
                                               const float* __restrict__ alpha,
                                               const bf16* __restrict__ hf,
                                               const bf16* __restrict__ zbuf,
                                               bf16* __restrict__ ybuf,
                                               int b, int l0) {
    int g = blockIdx.x;
    int h = g >> 6, nl = g & 63;
    int t0l = nl * 64;
    float alp = alpha[(size_t)(b * 24 + h) * 128 + (l0 >> 6) + nl];
    __shared__ float Ct[64][68];
    __shared__ float Hs[64][68];
    __shared__ float dfs[64];
    int tid = threadIdx.x;
    if (tid < 64) {
        float a = Aarr[(size_t)(t0l + tid) * 24 + h] * (1.f - alp);
        for (int off = 1; off < 64; off <<= 1) {
            float u = __shfl_up(a, off, 64);
            if (tid >= off) a += u;
        }
        dfs[tid] = expf(a);
    }
    int s = tid & 63, cw0 = tid >> 6;
    for (int it = 0; it < 16; ++it) {
        int row = cw0 + (it << 2);
        int t = t0l + row;
        Ct[s][row] = bf2f(xp[(size_t)t * NPROJ + h * 129 + 65 + s]) * invC[t * 24 + h];
        Hs[row][s] = bf2f(hf[(size_t)(h * SEG_CH + nl) * 4096 + (size_t)row * 64 + s]);
    }
    __syncthreads();
    int i0 = (tid >> 4) << 2, d0 = (tid & 15) << 2;
    float acc[4][4] = {};
    for (int ss = 0; ss < 64; ++ss) {
        const float4 c_ = *(const float4*)&Ct[ss][i0];
        const float4 h_ = *(const float4*)&Hs[ss][d0];
        const float cr[4] = {c_.x, c_.y, c_.z, c_.w};
        const float hr[4] = {h_.x, h_.y, h_.z, h_.w};
#pragma unroll
        for (int r = 0; r < 4; ++r)
#pragma unroll
            for (int q = 0; q < 4; ++q) acc[r][q] += cr[r] * hr[q];
    }
#pragma unroll
    for (int r = 0; r < 4; ++r) {
        int t = t0l + i0 + r;
        float df = dfs[i0 + r];
        size_t yoff = (size_t)t * DINNER + h * 64 + d0;
#pragma unroll
        for (int q = 0; q < 4; ++q) {
            float Y = clampf(bf2f(ybuf[yoff + q]) + df * acc[r][q], -100.f, 100.f);
            float zz = bf2f(zbuf[yoff + q]);
            ybuf[yoff + q] = f2bf(Y / (1.f + expf(-zz)));
        }
    }
}

// ---------------------------------------------------------------- launch
extern "C" void kernel_launch(void* const* d_in, const int* in_sizes, int n_in,
                              void* d_out, int out_size, void* d_ws, size_t ws_size,
                              hipStream_t stream) {
    const float* hs     = (const float*)d_in[0];
    const float* norm_w = (const float*)d_in[1];
    const float* w1     = (const float*)d_in[2];
    const float* b1     = (const float*)d_in[3];
    const float* cw     = (const float*)d_in[4];
    const float* cbias  = (const float*)d_in[5];
    const float* w2     = (const float*)d_in[6];
    const float* b2     = (const float*)d_in[7];
    const float* A_log  = (const float*)d_in[8];
    const float* l2ab   = (const float*)d_in[9];
    const float* l2b    = (const float*)d_in[10];
    const float* ema0   = (const float*)d_in[11];
    const float* w3     = (const float*)d_in[12];
    const float* b3     = (const float*)d_in[13];
    const float* rg     = (const float*)d_in[14];
    float* out = (float*)d_out;

    // big path needs ~169 MB of workspace; decide from ws_size (fixed per harness)
    const bool big = ws_size >= (size_t)175 * 1024 * 1024 ? false : false,
               BIG = ws_size >= (size_t)172 * 1024 * 1024;
    (void)big;

    char* base = (char*)d_ws;
    size_t off = 0;
    auto alloc = [&](size_t bytes) -> void* {
        void* p = base + off;
        off += (bytes + 255) & ~(size_t)255;
        return p;
    };
    // common
    bf16* w1bf  = (bf16*)alloc((size_t)2 * DINNER * DMODEL * 2);
    bf16* w2bf  = (bf16*)alloc((size_t)NPROJ * DINNER * 2);
    bf16* w3bf  = (bf16*)alloc((size_t)DMODEL * DINNER * 2);
    bf16* xn    = (bf16*)alloc((size_t)SEG_T * DMODEL * 2);
    bf16* zbuf  = (bf16*)alloc((size_t)SEG_T * DINNER * 2);
    bf16* ybuf  = (bf16*)alloc((size_t)SEG_T * DINNER * 2);
    bf16* hf    = (bf16*)alloc((size_t)NHEADS * SEG_CH * 4096 * 2);
    bf16* xhalo = (bf16*)alloc((size_t)2 * 3 * DINNER * 2);
    float* cs   = (float*)alloc((size_t)6144 * 4);
    float* alp  = (float*)alloc((size_t)6144 * 4);
    float* dch  = (float*)alloc((size_t)6144 * 4);
    float* carry= (float*)alloc((size_t)48 * 4096 * 4);
    // path-dependent (xp and per-token scalars)
    size_t ntokA = BIG ? (size_t)NTOK : (size_t)SEG_T;
    bf16* xp    = (bf16*)alloc(ntokA * NPROJ * 2);
    float* Aarr = (float*)alloc(ntokA * 24 * 4);
    float* invB = (float*)alloc(ntokA * 24 * 4);
    float* invC = (float*)alloc(ntokA * 24 * 4);
    bf16* xbuf  = ybuf;                    // phase-1 pre-conv x aliases ybuf
    bf16* xc_all = (bf16*)d_out;           // xc for ALL tokens (exact fit in d_out)

    {
        int n1 = 2 * DINNER * DMODEL / 4, n2 = NPROJ * DINNER / 4, n3 = DMODEL * DINNER / 4;
        k_cvt<<<(n1 + 255) / 256, 256, 0, stream>>>(w1, w1bf, n1);
        k_cvt<<<(n2 + 255) / 256, 256, 0, stream>>>(w2, w2bf, n2);
        k_cvt<<<(n3 + 255) / 256, 256, 0, stream>>>(w3, w3bf, n3);
    }

    const dim3 gX(DINNER / 128, SEG_T / 128);            // 12 x 32
    const dim3 gP((NPROJ + 127) / 128, SEG_T / 128);     // 25 x 32
    const dim3 gPall((NPROJ + 127) / 128, NTOK / 128);   // 25 x 128
    const dim3 gO(DMODEL / 128, SEG_T / 128);            // 6 x 32

    // ---------------- phase 1: front-end for all tokens; xc cached into d_out
    for (int s = 0; s < NSEG; ++s) {
        size_t t0 = (size_t)s * SEG_T;
        int l0 = (int)(t0 & (L_SEQ - 1));
        const float* hseg = hs + t0 * DMODEL;
        bf16* xc = xc_all + t0 * DINNER;
        k_rmsnorm<<<SEG_T, 256, 0, stream>>>(hseg, norm_w, xn);
        k_mgemm<bf16, 0><<<gX, 256, 0, stream>>>(xn, w1bf, b1, xbuf,
                                                 SEG_T, DINNER, DMODEL, nullptr, nullptr);
        k_save_halo<<<18, 256, 0, stream>>>(xbuf, xhalo + (size_t)((s + 1) & 1) * 3 * DINNER);
        k_conv_silu<<<dim3(DINNER / 256, SEG_T), 256, 0, stream>>>(
            xbuf, xhalo + (size_t)(s & 1) * 3 * DINNER, cw, cbias, xc, l0);
        if (!BIG) {
            int b = (int)(t0 >> 13);
            k_mgemm<bf16, 0><<<gP, 256, 0, stream>>>(xc, w2bf, b2, xp,
                                                     SEG_T, NPROJ, DINNER, nullptr, nullptr);
            k_prep<<<SEG_T * 24 / 4, 256, 0, stream>>>(xp, A_log, Aarr, invB, invC);
            k_surprise<<<NHEADS * SEG_CH, 256, 0, stream>>>(xp, xc, invB, cs, b, l0);
        }
    }
    if (BIG) {
        // single full-M x_proj GEMM + prep + surprise over all tokens
        k_mgemm<bf16, 0><<<gPall, 256, 0, stream>>>(xc_all, w2bf, b2, xp,
                                                    NTOK, NPROJ, DINNER, nullptr, nullptr);
        k_prep<<<NTOK * 24 / 4, 256, 0, stream>>>(xp, A_log, Aarr, invB, invC);
        k_surprise_all<<<6144, 256, 0, stream>>>(xp, xc_all, invB, cs);
    }
    k_alpha<<<24, 256, 0, stream>>>(cs, ema0, l2ab, l2b, alp);

    // ---------------- phase 2: SSM + output per segment
    for (int s = 0; s < NSEG; ++s) {
        size_t t0 = (size_t)s * SEG_T;
        int l0 = (int)(t0 & (L_SEQ - 1));
        int b  = (int)(t0 >> 13);
        const float* hseg = hs + t0 * DMODEL;
        bf16* xc = xc_all + t0 * DINNER;
        const bf16* xpS;
        const float* AarrS;
        const float* invBS;
        const float* invCS;
        k_rmsnorm<<<SEG_T, 256, 0, stream>>>(hseg, norm_w, xn);
        k_mgemm<bf16, 0><<<gX, 256, 0, stream>>>(xn, w1bf + (size_t)DINNER * DMODEL,
                                                 b1 + DINNER, zbuf,
                                                 SEG_T, DINNER, DMODEL, nullptr, nullptr);
        if (BIG) {
            xpS   = xp   + t0 * NPROJ;
            AarrS = Aarr + t0 * 24;
            invBS = invB + t0 * 24;
            invCS = invC + t0 * 24;
        } else {
            k_mgemm<bf16, 0><<<gP, 256, 0, stream>>>(xc, w2bf, b2, xp,
                                                     SEG_T, NPROJ, DINNER, nullptr, nullptr);
            k_prep<<<SEG_T * 24 / 4, 256, 0, stream>>>(xp, A_log, Aarr, invB, invC);
            xpS = xp; AarrS = Aarr; invBS = invB; invCS = invC;
        }
        k_intra<<<NHEADS * SEG_CH, 256, 0, stream>>>(xpS, xc, invBS, invCS, AarrS, alp, ybuf, b, l0);
        k_hchunk<<<NHEADS * SEG_CH, 256, 0, stream>>>(xpS, xc, invBS, AarrS, alp, hf, dch, b, l0);
        k_scan<<<384, 256, 0, stream>>>(hf, dch, carry, b, l0);
        k_inter<<<NHEADS * SEG_CH, 256, 0, stream>>>(xpS, invCS, AarrS, alp, hf, zbuf, ybuf, b, l0);
        k_mgemm<float, 1><<<gO, 256, 0, stream>>>(ybuf, w3bf, b3, out + t0 * DMODEL,
                                                  SEG_T, DMODEL, DINNER, hseg, rg);
    }
}

// Round 7
// 1204.650 us; speedup vs baseline: 6.6334x; 1.1202x over previous
//
#include <hip/hip_runtime.h>
#include <hip/hip_bf16.h>
#include <cstdint>
#include <cstddef>

#define L_SEQ   8192
#define DMODEL  768
#define NHEADS  24
#define DINNER  1536
#define NPROJ   3096      /* 24 * 129 */
#define NTOK    16384
#define SEG_T   4096      /* tokens per segment */
#define NSEG    4
#define SEG_CH  64        /* chunks per segment */
#define RMS_EPS 1.1920929e-07f

typedef __hip_bfloat16 bf16;
typedef __attribute__((ext_vector_type(8))) short bf8v;
typedef __attribute__((ext_vector_type(4))) float f4v;

__device__ __forceinline__ float clampf(float x, float lo, float hi) {
    return fminf(fmaxf(x, lo), hi);
}
__device__ __forceinline__ float bf2f(bf16 v) { return __bfloat162float(v); }
__device__ __forceinline__ bf16  f2bf(float v) { return __float2bfloat16(v); }
__device__ __forceinline__ short f2bs(float v) {
    bf16 b = __float2bfloat16(v);
    return *reinterpret_cast<short*>(&b);
}
__device__ __forceinline__ void st1(float* p, float v) { *p = v; }
__device__ __forceinline__ void st1(bf16* p, float v) { *p = f2bf(v); }
__device__ __forceinline__ void st4(float* p, float4 v) { *(float4*)p = v; }
__device__ __forceinline__ void st4(bf16* p, float4 v) {
    p[0] = f2bf(v.x); p[1] = f2bf(v.y); p[2] = f2bf(v.z); p[3] = f2bf(v.w);
}

// ---------------------------------------------------------------- f32 -> bf16 weight conversion
__global__ __launch_bounds__(256) void k_cvt(const float* __restrict__ s,
                                             bf16* __restrict__ d, int n4) {
    int i = blockIdx.x * 256 + threadIdx.x;
    if (i < n4) {
        float4 v = *(const float4*)&s[i * 4];
        st4(&d[i * 4], v);
    }
}

// ---------------------------------------------------------------- RMSNorm (f32 in, bf16 out)
__global__ __launch_bounds__(256) void k_rmsnorm(const float* __restrict__ hs,
                                                 const float* __restrict__ w,
                                                 bf16* __restrict__ xn) {
    int t = blockIdx.x;
    const float* p = hs + (size_t)t * DMODEL;
    float s = 0.f;
    for (int i = threadIdx.x; i < DMODEL; i += 256) { float v = p[i]; s += v * v; }
    for (int off = 32; off; off >>= 1) s += __shfl_xor(s, off, 64);
    __shared__ float ws4[4];
    int lane = threadIdx.x & 63, wv = threadIdx.x >> 6;
    if (lane == 0) ws4[wv] = s;
    __syncthreads();
    s = ws4[0] + ws4[1] + ws4[2] + ws4[3];
    float r = 1.0f / sqrtf(s * (1.0f / DMODEL) + RMS_EPS);
    bf16* o = xn + (size_t)t * DMODEL;
    for (int i = threadIdx.x; i < DMODEL; i += 256) o[i] = f2bf(p[i] * r * w[i]);
}

// ---------------------------------------------------------------- MFMA GEMM  C[M,N] = A[M,K] @ B[N,K]^T + bias
// 128x128 tile, BK=32, 4 waves, register-prefetch, L2-supertiled XCD swizzle.
// Requires gy % 8 == 0.
template <typename TC, int EPI>
__global__ __launch_bounds__(256) void k_mgemm(const bf16* __restrict__ A,
                                               const bf16* __restrict__ B,
                                               const float* __restrict__ bias,
                                               TC* __restrict__ C,
                                               int M, int N, int K,
                                               const float* __restrict__ resid,
                                               const float* __restrict__ gatep) {
    constexpr int LDR = 40;
    __shared__ short As[128 * LDR];
    __shared__ short Bs[128 * LDR];
    int tid = threadIdx.x;
    int lane = tid & 63, wid = tid >> 6;

    // ---- XCD supertile swizzle: XCD owns 16 contiguous M-tile rows; within,
    //      8-row A-stripes stay L2-resident while bx sweeps all N-tiles.
    int gx = gridDim.x, gy = gridDim.y;
    int bid = blockIdx.y * gx + blockIdx.x;
    int xcd = bid & 7, idx = bid >> 3;      // idx in [0, gx*gy/8)
    int bys = gy >> 3;                       // M-tile rows per XCD
    int gby = bys < 8 ? bys : 8;             // stripe height
    int sg  = idx / (gx * gby);
    int rem = idx - sg * (gx * gby);
    int bx  = rem / gby;
    int byl = rem - bx * gby;
    int by  = xcd * bys + sg * gby + byl;
    int m0 = by * 128, n0 = bx * 128;

    int wm = (wid >> 1) << 6, wn = (wid & 1) << 6;

    int r0 = tid >> 2, c0 = (tid & 3) << 3;
    int r1 = (tid + 256) >> 2, c1 = ((tid + 256) & 3) << 3;
    const bf16* Asrc0 = A + (size_t)(m0 + r0) * K + c0;
    const bf16* Asrc1 = A + (size_t)(m0 + r1) * K + c1;
    int nr0 = n0 + r0, nr1 = n0 + r1;
    const bf16* Bsrc0 = B + (size_t)nr0 * K + c0;
    const bf16* Bsrc1 = B + (size_t)nr1 * K + c1;
    bool bok0 = nr0 < N, bok1 = nr1 < N;

    f4v acc[4][4];
#pragma unroll
    for (int i = 0; i < 4; ++i)
#pragma unroll
        for (int j = 0; j < 4; ++j) acc[i][j] = (f4v){0.f, 0.f, 0.f, 0.f};

    const uint4 uz = make_uint4(0u, 0u, 0u, 0u);
    uint4 a0 = *(const uint4*)(const void*)Asrc0;
    uint4 a1 = *(const uint4*)(const void*)Asrc1;
    uint4 b0 = bok0 ? *(const uint4*)(const void*)Bsrc0 : uz;
    uint4 b1 = bok1 ? *(const uint4*)(const void*)Bsrc1 : uz;

    for (int k0 = 0; k0 < K; k0 += 32) {
        __syncthreads();
        *(uint4*)&As[r0 * LDR + c0] = a0;
        *(uint4*)&As[r1 * LDR + c1] = a1;
        *(uint4*)&Bs[r0 * LDR + c0] = b0;
        *(uint4*)&Bs[r1 * LDR + c1] = b1;
        __syncthreads();
        int kn = (k0 + 32 < K) ? k0 + 32 : k0;
        a0 = *(const uint4*)(const void*)(Asrc0 + kn);
        a1 = *(const uint4*)(const void*)(Asrc1 + kn);
        b0 = bok0 ? *(const uint4*)(const void*)(Bsrc0 + kn) : uz;
        b1 = bok1 ? *(const uint4*)(const void*)(Bsrc1 + kn) : uz;
        int row16 = lane & 15, kg = (lane >> 4) << 3;
        bf8v af[4], bfv[4];
#pragma unroll
        for (int fm = 0; fm < 4; ++fm)
            af[fm] = *(const bf8v*)&As[(wm + (fm << 4) + row16) * LDR + kg];
#pragma unroll
        for (int fn = 0; fn < 4; ++fn)
            bfv[fn] = *(const bf8v*)&Bs[(wn + (fn << 4) + row16) * LDR + kg];
#pragma unroll
        for (int fm = 0; fm < 4; ++fm)
#pragma unroll
            for (int fn = 0; fn < 4; ++fn)
                acc[fm][fn] = __builtin_amdgcn_mfma_f32_16x16x32_bf16(
                    af[fm], bfv[fn], acc[fm][fn], 0, 0, 0);
    }

    float gate = (EPI == 1) ? *gatep : 0.f;
    int rbase = m0 + wm + ((lane >> 4) << 2);
#pragma unroll
    for (int fn = 0; fn < 4; ++fn) {
        int col = n0 + wn + (fn << 4) + (lane & 15);
        if (col >= N) continue;
        float bc = bias[col];
#pragma unroll
        for (int fm = 0; fm < 4; ++fm) {
#pragma unroll
            for (int r = 0; r < 4; ++r) {
                int row = rbase + (fm << 4) + r;
                float v = acc[fm][fn][r] + bc;
                if (EPI == 1)
                    v = resid[(size_t)row * N + col] + clampf(v, -100.f, 100.f) * gate;
                st1(&C[(size_t)row * N + col], v);
            }
        }
    }
}

// ---------------------------------------------------------------- save last 3 rows of x for next segment's conv halo
__global__ __launch_bounds__(256) void k_save_halo(const bf16* __restrict__ x,
                                                   bf16* __restrict__ dst) {
    int i = blockIdx.x * 256 + threadIdx.x;
    if (i < 3 * DINNER) dst[i] = x[(size_t)(SEG_T - 3) * DINNER + i];
}

// ---------------------------------------------------------------- depthwise causal conv (k=4) + SiLU
__global__ __launch_bounds__(256) void k_conv_silu(const bf16* __restrict__ x,
                                                   const bf16* __restrict__ xh,
                                                   const float* __restrict__ cw,
                                                   const float* __restrict__ cb,
                                                   bf16* __restrict__ xc,
                                                   int l0) {
    int c = blockIdx.x * 256 + threadIdx.x;
    int r = blockIdx.y;
    int l = l0 + r;
    float acc = cb[c];
#pragma unroll
    for (int k = 0; k < 4; ++k) {
        int lp = l - 3 + k;
        if (lp < 0) continue;
        float v = (lp < l0) ? bf2f(xh[(size_t)(lp - l0 + 3) * DINNER + c])
                            : bf2f(x[(size_t)(lp - l0) * DINNER + c]);
        acc += cw[c * 4 + k] * v;
    }
    float sig = 1.f / (1.f + expf(-acc));
    xc[(size_t)r * DINNER + c] = f2bf(acc * sig);
}

// ---------------------------------------------------------------- per-(t,h): A value, 1/||B||, 1/||C||
__global__ __launch_bounds__(256) void k_prep(const bf16* __restrict__ xp,
                                              const float* __restrict__ A_log,
                                              float* __restrict__ Aarr,
                                              float* __restrict__ invB,
                                              float* __restrict__ invC) {
    int wv = threadIdx.x >> 6, lane = threadIdx.x & 63;
    int idx = blockIdx.x * 4 + wv;
    int t = idx / 24, h = idx - t * 24;
    const bf16* base = xp + (size_t)t * NPROJ + h * 129;
    float b = bf2f(base[1 + lane]), c = bf2f(base[65 + lane]);
    float sb = b * b, sc = c * c;
    for (int off = 32; off; off >>= 1) {
        sb += __shfl_xor(sb, off, 64);
        sc += __shfl_xor(sc, off, 64);
    }
    if (lane == 0) {
        invB[idx] = 1.f / fmaxf(sqrtf(sb), 1e-12f);
        invC[idx] = 1.f / fmaxf(sqrtf(sc), 1e-12f);
        float dt = clampf(bf2f(base[0]), -10.f, 10.f);
        float dts = clampf(log1pf(expf(dt)), 0.01f, 10.f);
        float A = clampf(A_log[h], -2.3f, -0.01f) * dts;
        Aarr[idx] = clampf(A, -20.f, -0.001f);
    }
}

// ---------------------------------------------------------------- chunk surprise via MFMA (shared body)
// D[s][d] = sum_c B[c][s] X[c][d]; cs = ||D||_F^2 / 4096
__device__ __forceinline__ void surprise_body(const bf16* xp, const bf16* xc,
                                              const float* invB, float* cs,
                                              int t0, int h, size_t cs_idx) {
    __shared__ short Ws[64 * 72];   // B^T : Ws[s][c]
    __shared__ short Xt[64 * 72];   // X^T : Xt[d][c]
    int tid = threadIdx.x, s = tid & 63, cg = tid >> 6;
    for (int it = 0; it < 16; ++it) {
        int c = cg + (it << 2);
        int t = t0 + c;
        Ws[s * 72 + c] = f2bs(bf2f(xp[(size_t)t * NPROJ + h * 129 + 1 + s]) * invB[t * 24 + h]);
        Xt[s * 72 + c] = *(const short*)&xc[(size_t)t * DINNER + h * 64 + s];
    }
    __syncthreads();
    int w = tid >> 6, lane = tid & 63;
    int r16 = lane & 15, kq = (lane >> 4) << 3;
    int strip = w << 4;
    f4v acc[4];
#pragma unroll
    for (int dt = 0; dt < 4; ++dt) acc[dt] = (f4v){0.f, 0.f, 0.f, 0.f};
#pragma unroll
    for (int ks = 0; ks < 2; ++ks) {
        bf8v af = *(const bf8v*)&Ws[(strip + r16) * 72 + ks * 32 + kq];
#pragma unroll
        for (int dt = 0; dt < 4; ++dt) {
            bf8v bf_ = *(const bf8v*)&Xt[((dt << 4) + r16) * 72 + ks * 32 + kq];
            acc[dt] = __builtin_amdgcn_mfma_f32_16x16x32_bf16(af, bf_, acc[dt], 0, 0, 0);
        }
    }
    float ss = 0.f;
#pragma unroll
    for (int dt = 0; dt < 4; ++dt)
#pragma unroll
        for (int r = 0; r < 4; ++r) ss += acc[dt][r] * acc[dt][r];
    for (int off = 32; off; off >>= 1) ss += __shfl_xor(ss, off, 64);
    __shared__ float ws4[4];
    if (lane == 0) ws4[w] = ss;
    __syncthreads();
    if (tid == 0) cs[cs_idx] = (ws4[0] + ws4[1] + ws4[2] + ws4[3]) * (1.f / 4096.f);
}

__global__ __launch_bounds__(256) void k_surprise(const bf16* __restrict__ xp,
                                                  const bf16* __restrict__ xc,
                                                  const float* __restrict__ invB,
                                                  float* __restrict__ cs,
                                                  int b, int l0) {
    int g = blockIdx.x;
    int h = g >> 6, nl = g & 63;
    surprise_body(xp, xc, invB, cs, nl * 64, h,
                  (size_t)(b * 24 + h) * 128 + (l0 >> 6) + nl);
}

__global__ __launch_bounds__(256) void k_surprise_all(const bf16* __restrict__ xp,
                                                      const bf16* __restrict__ xc,
                                                      const float* __restrict__ invB,
                                                      float* __restrict__ cs) {
    int g = blockIdx.x;                 // 0..6143
    int cg = g / 24, h = g - cg * 24;
    int b = cg >> 7, nl = cg & 127;
    surprise_body(xp, xc, invB, cs, cg * 64, h, (size_t)(b * 24 + h) * 128 + nl);
}

// ---------------------------------------------------------------- per-head EMA + alpha
__global__ __launch_bounds__(256) void k_alpha(const float* __restrict__ cs,
                                               const float* __restrict__ ema0,
                                               const float* __restrict__ l2ab,
                                               const float* __restrict__ l2b,
                                               float* __restrict__ alpha) {
    int h = blockIdx.x, tid = threadIdx.x;
    int b = tid >> 7, n = tid & 127;
    int gi = (b * 24 + h) * 128 + n;
    float v = cs[gi];
    float s = v;
    for (int off = 32; off; off >>= 1) s += __shfl_xor(s, off, 64);
    __shared__ float ws4[4];
    int lane = tid & 63, wv = tid >> 6;
    if (lane == 0) ws4[wv] = s;
    __syncthreads();
    float total = ws4[0] + ws4[1] + ws4[2] + ws4[3];
    float ema = 0.99f * ema0[h] + 0.01f * (total * (1.f / 256.f));
    float ab = 1.f - exp2f(clampf(l2ab[h], -3.32f, -0.015f));
    float beta = exp2f(clampf(l2b[h], -2.f, 2.f));
    float nz = v / (ema + 1e-6f);
    float boost = fmaxf(tanhf(beta * nz), 0.f);
    alpha[gi] = clampf(ab + (1.f - ab) * boost, 0.01f, 0.999f);
}

// ---------------------------------------------------------------- intra-chunk via MFMA
// CB[i][j] = sum_s C[i][s]B[j][s]; M = mask.decay ∘ CB; Y = M X
__global__ __launch_bounds__(256) void k_intra(const bf16* __restrict__ xp,
                                               const bf16* __restrict__ xc,
                                               const float* __restrict__ invB,
                                               const float* __restrict__ invC,
                                               const float* __restrict__ Aarr,
                                               const float* __restrict__ alpha,
                                               bf16* __restrict__ ybuf,
                                               int b, int l0) {
    int g = blockIdx.x;
    int h = g >> 6, nl = g & 63;
    int t0l = nl * 64;
    float alp = alpha[(size_t)(b * 24 + h) * 128 + (l0 >> 6) + nl];
    __shared__ short Cs[64 * 72];   // C rows [i][s]; reused as M [i][j]
    __shared__ short Bs[64 * 72];   // B rows [j][s]
    __shared__ short Xt[64 * 72];   // X^T   [d][c]
    __shared__ float Acs[64];
    int tid = threadIdx.x;
    if (tid < 64) {
        float a = Aarr[(size_t)(t0l + tid) * 24 + h] * (1.f - alp);
        for (int off = 1; off < 64; off <<= 1) {
            float u = __shfl_up(a, off, 64);
            if (tid >= off) a += u;
        }
        Acs[tid] = a;
    }
    int s = tid & 63, cg = tid >> 6;
    for (int it = 0; it < 16; ++it) {
        int c = cg + (it << 2);
        int t = t0l + c;
        const bf16* bp = xp + (size_t)t * NPROJ + h * 129;
        Bs[c * 72 + s] = f2bs(bf2f(bp[1 + s]) * invB[t * 24 + h]);
        Cs[c * 72 + s] = f2bs(bf2f(bp[65 + s]) * invC[t * 24 + h]);
        Xt[s * 72 + c] = *(const short*)&xc[(size_t)t * DINNER + h * 64 + s];
    }
    __syncthreads();
    int w = tid >> 6, lane = tid & 63;
    int r16 = lane & 15, kq = (lane >> 4) << 3;
    int strip = w << 4;
    f4v acc[4];
#pragma unroll
    for (int jt = 0; jt < 4; ++jt) acc[jt] = (f4v){0.f, 0.f, 0.f, 0.f};
#pragma unroll
    for (int ks = 0; ks < 2; ++ks) {
        bf8v af = *(const bf8v*)&Cs[(strip + r16) * 72 + ks * 32 + kq];
#pragma unroll
        for (int jt = 0; jt < 4; ++jt) {
            bf8v bf_ = *(const bf8v*)&Bs[((jt << 4) + r16) * 72 + ks * 32 + kq];
            acc[jt] = __builtin_amdgcn_mfma_f32_16x16x32_bf16(af, bf_, acc[jt], 0, 0, 0);
        }
    }
    __syncthreads();               // all CB reads of Cs complete
    short* Ms = Cs;                // overwrite C with masked M [i][j]
    int ibase = strip + ((lane >> 4) << 2);
#pragma unroll
    for (int jt = 0; jt < 4; ++jt) {
        int j = (jt << 4) + r16;
        float aj = Acs[j];
#pragma unroll
        for (int r = 0; r < 4; ++r) {
            int i = ibase + r;
            float m = (j <= i) ? expf(Acs[i] - aj) * acc[jt][r] : 0.f;
            Ms[i * 72 + j] = f2bs(m);
        }
    }
    __syncthreads();
    f4v accy[4];
#pragma unroll
    for (int dt = 0; dt < 4; ++dt) accy[dt] = (f4v){0.f, 0.f, 0.f, 0.f};
#pragma unroll
    for (int ks = 0; ks < 2; ++ks) {
        bf8v af = *(const bf8v*)&Ms[(strip + r16) * 72 + ks * 32 + kq];
#pragma unroll
        for (int dt = 0; dt < 4; ++dt) {
            bf8v xf = *(const bf8v*)&Xt[((dt << 4) + r16) * 72 + ks * 32 + kq];
            accy[dt] = __builtin_amdgcn_mfma_f32_16x16x32_bf16(af, xf, accy[dt], 0, 0, 0);
        }
    }
#pragma unroll
    for (int dt = 0; dt < 4; ++dt) {
        int d = (dt << 4) + r16;
#pragma unroll
        for (int r = 0; r < 4; ++r) {
            int i = ibase + r;
            ybuf[(size_t)(t0l + i) * DINNER + h * 64 + d] = f2bf(accy[dt][r]);
        }
    }
}

// ---------------------------------------------------------------- h_chunk_final + decay_chunk via MFMA
// D[s][d] = sum_c dte[c] B[c][s] X[c][d]
__global__ __launch_bounds__(256) void k_hchunk(const bf16* __restrict__ xp,
                                                const bf16* __restrict__ xc,
                                                const float* __restrict__ invB,
                                                const float* __restrict__ Aarr,
                                                const float* __restrict__ alpha,
                                                bf16* __restrict__ hf,
                                                float* __restrict__ dchunk,
                                                int b, int l0) {
    int g = blockIdx.x;
    int h = g >> 6, nl = g & 63;
    int t0l = nl * 64;
    size_t gidx = (size_t)(b * 24 + h) * 128 + (l0 >> 6) + nl;
    float alp = alpha[gidx];
    __shared__ short Ws[64 * 72];   // (dte.B)^T : Ws[s][c]
    __shared__ short Xt[64 * 72];   // X^T       : Xt[d][c]
    __shared__ float dte[64];
    int tid = threadIdx.x;
    if (tid < 64) {
        float a = Aarr[(size_t)(t0l + tid) * 24 + h] * (1.f - alp);
        for (int off = 1; off < 64; off <<= 1) {
            float u = __shfl_up(a, off, 64);
            if (tid >= off) a += u;
        }
        float total = __shfl(a, 63, 64);
        dte[tid] = expf(total - a);
        if (tid == 0) dchunk[gidx] = expf(total);
    }
    __syncthreads();               // dte ready before staging uses it
    int s = tid & 63, cg = tid >> 6;
    for (int it = 0; it < 16; ++it) {
        int c = cg + (it << 2);
        int t = t0l + c;
        Ws[s * 72 + c] = f2bs(bf2f(xp[(size_t)t * NPROJ + h * 129 + 1 + s]) * invB[t * 24 + h] * dte[c]);
        Xt[s * 72 + c] = *(const short*)&xc[(size_t)t * DINNER + h * 64 + s];
    }
    __syncthreads();
    int w = tid >> 6, lane = tid & 63;
    int r16 = lane & 15, kq = (lane >> 4) << 3;
    int strip = w << 4;
    f4v acc[4];
#pragma unroll
    for (int dt = 0; dt < 4; ++dt) acc[dt] = (f4v){0.f, 0.f, 0.f, 0.f};
#pragma unroll
    for (int ks = 0; ks < 2; ++ks) {
        bf8v af = *(const bf8v*)&Ws[(strip + r16) * 72 + ks * 32 + kq];
#pragma unroll
        for (int dt = 0; dt < 4; ++dt) {
            bf8v xf = *(const bf8v*)&Xt[((dt << 4) + r16) * 72 + ks * 32 + kq];
            acc[dt] = __builtin_amdgcn_mfma_f32_16x16x32_bf16(af, xf, acc[dt], 0, 0, 0);
        }
    }
    size_t hbase = (size_t)(h * SEG_CH + nl) * 4096;
    int sbase = strip + ((lane >> 4) << 2);
#pragma unroll
    for (int dt = 0; dt < 4; ++dt) {
        int d = (dt << 4) + r16;
#pragma unroll
        for (int r = 0; r < 4; ++r)
            hf[hbase + (size_t)(sbase + r) * 64 + d] = f2bf(acc[dt][r]);
    }
}

// ---------------------------------------------------------------- chunk scan (prefetched)
__global__ __launch_bounds__(256) void k_scan(bf16* __restrict__ hf,
                                              const float* __restrict__ dchunk,
                                              float* __restrict__ carry,
                                              int b, int l0) {
    int h = blockIdx.x >> 4;
    int e = ((blockIdx.x & 15) << 8) + threadIdx.x;
    int bh = b * 24 + h;
    float c = (l0 == 0) ? 0.f : carry[(size_t)bh * 4096 + e];
    size_t a = (size_t)h * SEG_CH * 4096 + e;
    float v = bf2f(hf[a]);
    const float* dcp = dchunk + (size_t)bh * 128 + (l0 >> 6);
    for (int nl = 0; nl < SEG_CH; ++nl) {
        float dc = dcp[nl];
        float vn = (nl + 1 < SEG_CH) ? bf2f(hf[a + 4096]) : 0.f;
        hf[a] = f2bf(c);
        c = dc * c + v;
        v = vn;
        a += 4096;
    }
    carry[(size_t)bh * 4096 + e] = c;
}

// ---------------------------------------------------------------- Y_inter + gate via MFMA (in place on ybuf)
// Yi[i][d] = sum_s C[i][s] h[s][d]; Y = clip(Yintra + df[i]*Yi)*sigmoid(z)
__global__ __launch_bounds__(256) void k_inter(const bf16* __restrict__ xp,
                                               const float* __restrict__ invC,
                                               const float* __restrict__ Aarr,
                                               const float* __restrict__ alpha,
                                               const bf16* __restrict__ hf,
                                               const bf16* __restrict__ zbuf,
                                               bf16* __restrict__ ybuf,
                                               int b, int l0) {
    int g = blockIdx.x;
    int h = g >> 6, nl = g & 63;
    int t0l = nl * 64;
    float alp = alpha[(size_t)(b * 24 + h) * 128 + (l0 >> 6) + nl];
    __shared__ short Cs[64 * 72];   // C rows [i][s]
    __shared__ short Ht[64 * 72];   // h^T    [d][s]
    __shared__ float dfs[64];
    int tid = threadIdx.x;
    if (tid < 64) {
        float a = Aarr[(size_t)(t0l + tid) * 24 + h] * (1.f - alp);
        for (int off = 1; off < 64; off <<= 1) {
            float u = __shfl_up(a, off, 64);
            if (tid >= off) a += u;
        }
        dfs[tid] = expf(a);
    }
    int s = tid & 63, cg = tid >> 6;
    size_t hbase = (size_t)(h * SEG_CH + nl) * 4096;
    for (int it = 0; it < 16; ++it) {
        int c = cg + (it << 2);
        int t = t0l + c;
        Cs[c * 72 + s] = f2bs(bf2f(xp[(size_t)t * NPROJ + h * 129 + 65 + s]) * invC[t * 24 + h]);
        Ht[s * 72 + c] = *(const short*)&hf[hbase + (size_t)c * 64 + s];
    }
    __syncthreads();
    int w = tid >> 6, lane = tid & 63;
    int r16 = lane & 15, kq = (lane >> 4) << 3;
    int strip = w << 4;
    f4v acc[4];
#pragma unroll
    for (int dt = 0; dt < 4; ++dt) acc[dt] = (f4v){0.f, 0.f, 0.f, 0.f};
#pragma unroll
    for (int ks = 0; ks < 2; ++ks) {
        bf8v af = *(const bf8v*)&Cs[(strip + r16) * 72 + ks * 32 + kq];
#pragma unroll
        for (int dt = 0; dt < 4; ++dt) {
            bf8v hfr = *(const bf8v*)&Ht[((dt << 4) + r16) * 72 + ks * 32 + kq];
            acc[dt] = __builtin_amdgcn_mfma_f32_16x16x32_bf16(af, hfr, acc[dt], 0, 0, 0);
        }
    }
    int ibase = strip + ((lane >> 4) << 2);
#pragma unroll
    for (int dt = 0; dt < 4; ++dt) {
        int d = (dt << 4) + r16;
#pragma unroll
        for (int r = 0; r < 4; ++r) {
            int i = ibase + r;
            float df = dfs[i];
            size_t yoff = (size_t)(t0l + i) * DINNER + h * 64 + d;
            float Y = clampf(bf2f(ybuf[yoff]) + df * acc[dt][r], -100.f, 100.f);
            float zz = bf2f(zbuf[yoff]);
            ybuf[yoff] = f2bf(Y / (1.f + expf(-zz)));
        }
    }
}

// ---------------------------------------------------------------- launch
extern "C" void kernel_launch(void* const* d_in, const int* in_sizes, int n_in,
                              void* d_out, int out_size, void* d_ws, size_t ws_size,
                              hipStream_t stream) {
    const float* hs     = (const float*)d_in[0];
    const float* norm_w = (const float*)d_in[1];
    const float* w1     = (const float*)d_in[2];
    const float* b1     = (const float*)d_in[3];
    const float* cw     = (const float*)d_in[4];
    const float* cbias  = (const float*)d_in[5];
    const float* w2     = (const float*)d_in[6];
    const float* b2     = (const float*)d_in[7];
    const float* A_log  = (const float*)d_in[8];
    const float* l2ab   = (const float*)d_in[9];
    const float* l2b    = (const float*)d_in[10];
    const float* ema0   = (const float*)d_in[11];
    const float* w3     = (const float*)d_in[12];
    const float* b3     = (const float*)d_in[13];
    const float* rg     = (const float*)d_in[14];
    float* out = (float*)d_out;

    const bool BIG = ws_size >= (size_t)172 * 1024 * 1024;

    char* base = (char*)d_ws;
    size_t off = 0;
    auto alloc = [&](size_t bytes) -> void* {
        void* p = base + off;
        off += (bytes + 255) & ~(size_t)255;
        return p;
    };
    bf16* w1bf  = (bf16*)alloc((size_t)2 * DINNER * DMODEL * 2);
    bf16* w2bf  = (bf16*)alloc((size_t)NPROJ * DINNER * 2);
    bf16* w3bf  = (bf16*)alloc((size_t)DMODEL * DINNER * 2);
    bf16* xn    = (bf16*)alloc((size_t)SEG_T * DMODEL * 2);
    bf16* zbuf  = (bf16*)alloc((size_t)SEG_T * DINNER * 2);
    bf16* ybuf  = (bf16*)alloc((size_t)SEG_T * DINNER * 2);
    bf16* hf    = (bf16*)alloc((size_t)NHEADS * SEG_CH * 4096 * 2);
    bf16* xhalo = (bf16*)alloc((size_t)2 * 3 * DINNER * 2);
    float* cs   = (float*)alloc((size_t)6144 * 4);
    float* alp  = (float*)alloc((size_t)6144 * 4);
    float* dch  = (float*)alloc((size_t)6144 * 4);
    float* carry= (float*)alloc((size_t)48 * 4096 * 4);
    size_t ntokA = BIG ? (size_t)NTOK : (size_t)SEG_T;
    bf16* xp    = (bf16*)alloc(ntokA * NPROJ * 2);
    float* Aarr = (float*)alloc(ntokA * 24 * 4);
    float* invB = (float*)alloc(ntokA * 24 * 4);
    float* invC = (float*)alloc(ntokA * 24 * 4);
    bf16* xbuf  = ybuf;
    bf16* xc_all = (bf16*)d_out;

    {
        int n1 = 2 * DINNER * DMODEL / 4, n2 = NPROJ * DINNER / 4, n3 = DMODEL * DINNER / 4;
        k_cvt<<<(n1 + 255) / 256, 256, 0, stream>>>(w1, w1bf, n1);
        k_cvt<<<(n2 + 255) / 256, 256, 0, stream>>>(w2, w2bf, n2);
        k_cvt<<<(n3 + 255) / 256, 256, 0, stream>>>(w3, w3bf, n3);
    }

    const dim3 gX(DINNER / 128, SEG_T / 128);            // 12 x 32
    const dim3 gP((NPROJ + 127) / 128, SEG_T / 128);     // 25 x 32
    const dim3 gPall((NPROJ + 127) / 128, NTOK / 128);   // 25 x 128
    const dim3 gO(DMODEL / 128, SEG_T / 128);            // 6 x 32

    // ---------------- phase 1: front-end for all tokens; xc cached into d_out
    for (int s = 0; s < NSEG; ++s) {
        size_t t0 = (size_t)s * SEG_T;
        int l0 = (int)(t0 & (L_SEQ - 1));
        const float* hseg = hs + t0 * DMODEL;
        bf16* xc = xc_all + t0 * DINNER;
        k_rmsnorm<<<SEG_T, 256, 0, stream>>>(hseg, norm_w, xn);
        k_mgemm<bf16, 0><<<gX, 256, 0, stream>>>(xn, w1bf, b1, xbuf,
                                                 SEG_T, DINNER, DMODEL, nullptr, nullptr);
        k_save_halo<<<18, 256, 0, stream>>>(xbuf, xhalo + (size_t)((s + 1) & 1) * 3 * DINNER);
        k_conv_silu<<<dim3(DINNER / 256, SEG_T), 256, 0, stream>>>(
            xbuf, xhalo + (size_t)(s & 1) * 3 * DINNER, cw, cbias, xc, l0);
        if (!BIG) {
            int b = (int)(t0 >> 13);
            k_mgemm<bf16, 0><<<gP, 256, 0, stream>>>(xc, w2bf, b2, xp,
                                                     SEG_T, NPROJ, DINNER, nullptr, nullptr);
            k_prep<<<SEG_T * 24 / 4, 256, 0, stream>>>(xp, A_log, Aarr, invB, invC);
            k_surprise<<<NHEADS * SEG_CH, 256, 0, stream>>>(xp, xc, invB, cs, b, l0);
        }
    }
    if (BIG) {
        k_mgemm<bf16, 0><<<gPall, 256, 0, stream>>>(xc_all, w2bf, b2, xp,
                                                    NTOK, NPROJ, DINNER, nullptr, nullptr);
        k_prep<<<NTOK * 24 / 4, 256, 0, stream>>>(xp, A_log, Aarr, invB, invC);
        k_surprise_all<<<6144, 256, 0, stream>>>(xp, xc_all, invB, cs);
    }
    k_alpha<<<24, 256, 0, stream>>>(cs, ema0, l2ab, l2b, alp);

    // ---------------- phase 2: SSM + output per segment
    for (int s = 0; s < NSEG; ++s) {
        size_t t0 = (size_t)s * SEG_T;
        int l0 = (int)(t0 & (L_SEQ - 1));
        int b  = (int)(t0 >> 13);
        const float* hseg = hs + t0 * DMODEL;
        bf16* xc = xc_all + t0 * DINNER;
        const bf16* xpS;
        const float* AarrS;
        const float* invBS;
        const float* invCS;
        k_rmsnorm<<<SEG_T, 256, 0, stream>>>(hseg, norm_w, xn);
        k_mgemm<bf16, 0><<<gX, 256, 0, stream>>>(xn, w1bf + (size_t)DINNER * DMODEL,
                                                 b1 + DINNER, zbuf,
                                                 SEG_T, DINNER, DMODEL, nullptr, nullptr);
        if (BIG) {
            xpS   = xp   + t0 * NPROJ;
            AarrS = Aarr + t0 * 24;
            invBS = invB + t0 * 24;
            invCS = invC + t0 * 24;
        } else {
            k_mgemm<bf16, 0><<<gP, 256, 0, stream>>>(xc, w2bf, b2, xp,
                                                     SEG_T, NPROJ, DINNER, nullptr, nullptr);
            k_prep<<<SEG_T * 24 / 4, 256, 0, stream>>>(xp, A_log, Aarr, invB, invC);
            xpS = xp; AarrS = Aarr; invBS = invB; invCS = invC;
        }
        k_intra<<<NHEADS * SEG_CH, 256, 0, stream>>>(xpS, xc, invBS, invCS, AarrS, alp, ybuf, b, l0);
        k_hchunk<<<NHEADS * SEG_CH, 256, 0, stream>>>(xpS, xc, invBS, AarrS, alp, hf, dch, b, l0);
        k_scan<<<384, 256, 0, stream>>>(hf, dch, carry, b, l0);
        k_inter<<<NHEADS * SEG_CH, 256, 0, stream>>>(xpS, invCS, AarrS, alp, hf, zbuf, ybuf, b, l0);
        k_mgemm<float, 1><<<gO, 256, 0, stream>>>(ybuf, w3bf, b3, out + t0 * DMODEL,
                                                  SEG_T, DMODEL, DINNER, hseg, rg);
    }
}

// Round 8
// 1002.189 us; speedup vs baseline: 7.9735x; 1.2020x over previous
//
#include <hip/hip_runtime.h>
#include <hip/hip_bf16.h>
#include <cstdint>
#include <cstddef>

#define L_SEQ   8192
#define DMODEL  768
#define NHEADS  24
#define DINNER  1536
#define NPROJ   3096      /* 24 * 129 */
#define NPROJP  3200      /* padded weight rows for gload_lds */
#define NTOK    16384
#define SEG_T   4096      /* tokens per segment */
#define NSEG    4
#define SEG_CH  64        /* chunks per segment */
#define RMS_EPS 1.1920929e-07f

typedef __hip_bfloat16 bf16;
typedef __attribute__((ext_vector_type(8))) short bf8v;
typedef __attribute__((ext_vector_type(4))) float f4v;

__device__ __forceinline__ float clampf(float x, float lo, float hi) {
    return fminf(fmaxf(x, lo), hi);
}
__device__ __forceinline__ float bf2f(bf16 v) { return __bfloat162float(v); }
__device__ __forceinline__ bf16  f2bf(float v) { return __float2bfloat16(v); }
__device__ __forceinline__ short f2bs(float v) {
    bf16 b = __float2bfloat16(v);
    return *reinterpret_cast<short*>(&b);
}
__device__ __forceinline__ void st1(float* p, float v) { *p = v; }
__device__ __forceinline__ void st1(bf16* p, float v) { *p = f2bf(v); }
__device__ __forceinline__ void st4(float* p, float4 v) { *(float4*)p = v; }
__device__ __forceinline__ void st4(bf16* p, float4 v) {
    p[0] = f2bf(v.x); p[1] = f2bf(v.y); p[2] = f2bf(v.z); p[3] = f2bf(v.w);
}

#define GLOAD16(gsrc, ldst) __builtin_amdgcn_global_load_lds( \
    (const __attribute__((address_space(1))) void*)(gsrc),    \
    (__attribute__((address_space(3))) void*)(ldst), 16, 0, 0)

// ---------------------------------------------------------------- f32 -> bf16 weight conversion
__global__ __launch_bounds__(256) void k_cvt(const float* __restrict__ s,
                                             bf16* __restrict__ d, int n4) {
    int i = blockIdx.x * 256 + threadIdx.x;
    if (i < n4) {
        float4 v = *(const float4*)&s[i * 4];
        st4(&d[i * 4], v);
    }
}
__global__ __launch_bounds__(256) void k_zero(bf16* __restrict__ d, int n) {
    int i = blockIdx.x * 256 + threadIdx.x;
    if (i < n) d[i] = f2bf(0.f);
}

// ---------------------------------------------------------------- RMSNorm (f32 in, bf16 out)
__global__ __launch_bounds__(256) void k_rmsnorm(const float* __restrict__ hs,
                                                 const float* __restrict__ w,
                                                 bf16* __restrict__ xn) {
    int t = blockIdx.x;
    const float* p = hs + (size_t)t * DMODEL;
    float s = 0.f;
    for (int i = threadIdx.x; i < DMODEL; i += 256) { float v = p[i]; s += v * v; }
    for (int off = 32; off; off >>= 1) s += __shfl_xor(s, off, 64);
    __shared__ float ws4[4];
    int lane = threadIdx.x & 63, wv = threadIdx.x >> 6;
    if (lane == 0) ws4[wv] = s;
    __syncthreads();
    s = ws4[0] + ws4[1] + ws4[2] + ws4[3];
    float r = 1.0f / sqrtf(s * (1.0f / DMODEL) + RMS_EPS);
    bf16* o = xn + (size_t)t * DMODEL;
    for (int i = threadIdx.x; i < DMODEL; i += 256) o[i] = f2bf(p[i] * r * w[i]);
}

// ---------------------------------------------------------------- MFMA GEMM  C[M,N] = A[M,K] @ B[N,K]^T + bias
// 128x128 tile, BK=32, 4 waves, global_load_lds staging, 1 barrier/K-step
// double buffer, L2-supertiled XCD swizzle. Requires gy % 8 == 0 and all
// B rows [n0, n0+127] readable (weights padded to multiple of 128 rows).
template <typename TC, int EPI>
__global__ __launch_bounds__(256) void k_mgemm(const bf16* __restrict__ A,
                                               const bf16* __restrict__ B,
                                               const float* __restrict__ bias,
                                               TC* __restrict__ C,
                                               int M, int N, int K,
                                               const float* __restrict__ resid,
                                               const float* __restrict__ gatep) {
    __shared__ short As[2][128 * 32];   // linear [row][32 shorts] = 64B rows
    __shared__ short Bs[2][128 * 32];
    int tid = threadIdx.x;
    int lane = tid & 63, w = tid >> 6;

    // ---- XCD supertile swizzle
    int gx = gridDim.x, gy = gridDim.y;
    int bid = blockIdx.y * gx + blockIdx.x;
    int xcd = bid & 7, idx = bid >> 3;
    int bys = gy >> 3;
    int gby = bys < 8 ? bys : 8;
    int sg  = idx / (gx * gby);
    int rem = idx - sg * (gx * gby);
    int bx  = rem / gby;
    int byl = rem - bx * gby;
    int by  = xcd * bys + sg * gby + byl;
    int m0 = by * 128, n0 = bx * 128;

    int wm = (w >> 1) << 6, wn = (w & 1) << 6;

    // staging: wave w owns rows w*32..w*32+31 (2 issues of 16 rows each)
    const size_t rowskip = (size_t)16 * K * 2;     // 16 rows in bytes
    const char* Ag = (const char*)(A + (size_t)(m0 + (w << 5) + (lane >> 2)) * K) + (lane & 3) * 16;
    const char* Bg = (const char*)(B + (size_t)(n0 + (w << 5) + (lane >> 2)) * K) + (lane & 3) * 16;
    short* Al0 = &As[0][(w << 5) * 32];
    short* Bl0 = &Bs[0][(w << 5) * 32];
    short* Al1 = &As[1][(w << 5) * 32];
    short* Bl1 = &Bs[1][(w << 5) * 32];

    f4v acc[4][4];
#pragma unroll
    for (int i = 0; i < 4; ++i)
#pragma unroll
        for (int j = 0; j < 4; ++j) acc[i][j] = (f4v){0.f, 0.f, 0.f, 0.f};

    auto stage = [&](int buf, int k0) {
        size_t kb = (size_t)k0 * 2;
        short* Al = buf ? Al1 : Al0;
        short* Bl = buf ? Bl1 : Bl0;
        GLOAD16(Ag + kb,           Al);
        GLOAD16(Ag + kb + rowskip, Al + 16 * 32);
        GLOAD16(Bg + kb,           Bl);
        GLOAD16(Bg + kb + rowskip, Bl + 16 * 32);
    };

    stage(0, 0);
    int cur = 0;
    int row16 = lane & 15, kg = (lane >> 4) << 3;
    for (int k0 = 0; k0 < K; k0 += 32) {
        __syncthreads();                 // drains vmcnt: buf[cur] ready; prev reads done
        if (k0 + 32 < K) stage(cur ^ 1, k0 + 32);
        const short* Ab = As[cur];
        const short* Bb = Bs[cur];
        bf8v af[4], bfv[4];
#pragma unroll
        for (int fm = 0; fm < 4; ++fm)
            af[fm] = *(const bf8v*)&Ab[(wm + (fm << 4) + row16) * 32 + kg];
#pragma unroll
        for (int fn = 0; fn < 4; ++fn)
            bfv[fn] = *(const bf8v*)&Bb[(wn + (fn << 4) + row16) * 32 + kg];
#pragma unroll
        for (int fm = 0; fm < 4; ++fm)
#pragma unroll
            for (int fn = 0; fn < 4; ++fn)
                acc[fm][fn] = __builtin_amdgcn_mfma_f32_16x16x32_bf16(
                    af[fm], bfv[fn], acc[fm][fn], 0, 0, 0);
        cur ^= 1;
    }

    float gate = (EPI == 1) ? *gatep : 0.f;
    int rbase = m0 + wm + ((lane >> 4) << 2);
#pragma unroll
    for (int fn = 0; fn < 4; ++fn) {
        int col = n0 + wn + (fn << 4) + (lane & 15);
        if (col >= N) continue;
        float bc = bias[col];
#pragma unroll
        for (int fm = 0; fm < 4; ++fm) {
#pragma unroll
            for (int r = 0; r < 4; ++r) {
                int row = rbase + (fm << 4) + r;
                float v = acc[fm][fn][r] + bc;
                if (EPI == 1)
                    v = resid[(size_t)row * N + col] + clampf(v, -100.f, 100.f) * gate;
                st1(&C[(size_t)row * N + col], v);
            }
        }
    }
}

// ---------------------------------------------------------------- save last 3 rows of x for next segment's conv halo
__global__ __launch_bounds__(256) void k_save_halo(const bf16* __restrict__ x,
                                                   bf16* __restrict__ dst) {
    int i = blockIdx.x * 256 + threadIdx.x;
    if (i < 3 * DINNER) dst[i] = x[(size_t)(SEG_T - 3) * DINNER + i];
}

// ---------------------------------------------------------------- depthwise causal conv (k=4) + SiLU
__global__ __launch_bounds__(256) void k_conv_silu(const bf16* __restrict__ x,
                                                   const bf16* __restrict__ xh,
                                                   const float* __restrict__ cw,
                                                   const float* __restrict__ cb,
                                                   bf16* __restrict__ xc,
                                                   int l0) {
    int c = blockIdx.x * 256 + threadIdx.x;
    int r = blockIdx.y;
    int l = l0 + r;
    float acc = cb[c];
#pragma unroll
    for (int k = 0; k < 4; ++k) {
        int lp = l - 3 + k;
        if (lp < 0) continue;
        float v = (lp < l0) ? bf2f(xh[(size_t)(lp - l0 + 3) * DINNER + c])
                            : bf2f(x[(size_t)(lp - l0) * DINNER + c]);
        acc += cw[c * 4 + k] * v;
    }
    float sig = 1.f / (1.f + expf(-acc));
    xc[(size_t)r * DINNER + c] = f2bf(acc * sig);
}

// ---------------------------------------------------------------- per-(t,h): A value, 1/||B||, 1/||C||
__global__ __launch_bounds__(256) void k_prep(const bf16* __restrict__ xp,
                                              const float* __restrict__ A_log,
                                              float* __restrict__ Aarr,
                                              float* __restrict__ invB,
                                              float* __restrict__ invC) {
    int wv = threadIdx.x >> 6, lane = threadIdx.x & 63;
    int idx = blockIdx.x * 4 + wv;
    int t = idx / 24, h = idx - t * 24;
    const bf16* base = xp + (size_t)t * NPROJ + h * 129;
    float b = bf2f(base[1 + lane]), c = bf2f(base[65 + lane]);
    float sb = b * b, sc = c * c;
    for (int off = 32; off; off >>= 1) {
        sb += __shfl_xor(sb, off, 64);
        sc += __shfl_xor(sc, off, 64);
    }
    if (lane == 0) {
        invB[idx] = 1.f / fmaxf(sqrtf(sb), 1e-12f);
        invC[idx] = 1.f / fmaxf(sqrtf(sc), 1e-12f);
        float dt = clampf(bf2f(base[0]), -10.f, 10.f);
        float dts = clampf(log1pf(expf(dt)), 0.01f, 10.f);
        float A = clampf(A_log[h], -2.3f, -0.01f) * dts;
        Aarr[idx] = clampf(A, -20.f, -0.001f);
    }
}

// ---------------------------------------------------------------- chunk surprise via MFMA (shared body)
__device__ __forceinline__ void surprise_body(const bf16* xp, const bf16* xc,
                                              const float* invB, float* cs,
                                              int t0, int h, size_t cs_idx) {
    __shared__ short Ws[64 * 72];   // B^T : Ws[s][c]
    __shared__ short Xt[64 * 72];   // X^T : Xt[d][c]
    int tid = threadIdx.x, s = tid & 63, cg = tid >> 6;
    for (int it = 0; it < 16; ++it) {
        int c = cg + (it << 2);
        int t = t0 + c;
        Ws[s * 72 + c] = f2bs(bf2f(xp[(size_t)t * NPROJ + h * 129 + 1 + s]) * invB[t * 24 + h]);
        Xt[s * 72 + c] = *(const short*)&xc[(size_t)t * DINNER + h * 64 + s];
    }
    __syncthreads();
    int w = tid >> 6, lane = tid & 63;
    int r16 = lane & 15, kq = (lane >> 4) << 3;
    int strip = w << 4;
    f4v acc[4];
#pragma unroll
    for (int dt = 0; dt < 4; ++dt) acc[dt] = (f4v){0.f, 0.f, 0.f, 0.f};
#pragma unroll
    for (int ks = 0; ks < 2; ++ks) {
        bf8v af = *(const bf8v*)&Ws[(strip + r16) * 72 + ks * 32 + kq];
#pragma unroll
        for (int dt = 0; dt < 4; ++dt) {
            bf8v bf_ = *(const bf8v*)&Xt[((dt << 4) + r16) * 72 + ks * 32 + kq];
            acc[dt] = __builtin_amdgcn_mfma_f32_16x16x32_bf16(af, bf_, acc[dt], 0, 0, 0);
        }
    }
    float ss = 0.f;
#pragma unroll
    for (int dt = 0; dt < 4; ++dt)
#pragma unroll
        for (int r = 0; r < 4; ++r) ss += acc[dt][r] * acc[dt][r];
    for (int off = 32; off; off >>= 1) ss += __shfl_xor(ss, off, 64);
    __shared__ float ws4[4];
    if (lane == 0) ws4[w] = ss;
    __syncthreads();
    if (tid == 0) cs[cs_idx] = (ws4[0] + ws4[1] + ws4[2] + ws4[3]) * (1.f / 4096.f);
}

__global__ __launch_bounds__(256) void k_surprise(const bf16* __restrict__ xp,
                                                  const bf16* __restrict__ xc,
                                                  const float* __restrict__ invB,
                                                  float* __restrict__ cs,
                                                  int b, int l0) {
    int g = blockIdx.x;
    int h = g >> 6, nl = g & 63;
    surprise_body(xp, xc, invB, cs, nl * 64, h,
                  (size_t)(b * 24 + h) * 128 + (l0 >> 6) + nl);
}

__global__ __launch_bounds__(256) void k_surprise_all(const bf16* __restrict__ xp,
                                                      const bf16* __restrict__ xc,
                                                      const float* __restrict__ invB,
                                                      float* __restrict__ cs) {
    int g = blockIdx.x;                 // 0..6143
    int cg = g / 24, h = g - cg * 24;
    int b = cg >> 7, nl = cg & 127;
    surprise_body(xp, xc, invB, cs, cg * 64, h, (size_t)(b * 24 + h) * 128 + nl);
}

// ---------------------------------------------------------------- per-head EMA + alpha
__global__ __launch_bounds__(256) void k_alpha(const float* __restrict__ cs,
                                               const float* __restrict__ ema0,
                                               const float* __restrict__ l2ab,
                                               const float* __restrict__ l2b,
                                               float* __restrict__ alpha) {
    int h = blockIdx.x, tid = threadIdx.x;
    int b = tid >> 7, n = tid & 127;
    int gi = (b * 24 + h) * 128 + n;
    float v = cs[gi];
    float s = v;
    for (int off = 32; off; off >>= 1) s += __shfl_xor(s, off, 64);
    __shared__ float ws4[4];
    int lane = tid & 63, wv = tid >> 6;
    if (lane == 0) ws4[wv] = s;
    __syncthreads();
    float total = ws4[0] + ws4[1] + ws4[2] + ws4[3];
    float ema = 0.99f * ema0[h] + 0.01f * (total * (1.f / 256.f));
    float ab = 1.f - exp2f(clampf(l2ab[h], -3.32f, -0.015f));
    float beta = exp2f(clampf(l2b[h], -2.f, 2.f));
    float nz = v / (ema + 1e-6f);
    float boost = fmaxf(tanhf(beta * nz), 0.f);
    alpha[gi] = clampf(ab + (1.f - ab) * boost, 0.01f, 0.999f);
}

// ---------------------------------------------------------------- intra-chunk via MFMA
__global__ __launch_bounds__(256) void k_intra(const bf16* __restrict__ xp,
                                               const bf16* __restrict__ xc,
                                               const float* __restrict__ invB,
                                               const float* __restrict__ invC,
                                               const float* __restrict__ Aarr,
                                               const float* __restrict__ alpha,
                                               bf16* __restrict__ ybuf,
                                               int b, int l0) {
    int g = blockIdx.x;
    int h = g >> 6, nl = g & 63;
    int t0l = nl * 64;
    float alp = alpha[(size_t)(b * 24 + h) * 128 + (l0 >> 6) + nl];
    __shared__ short Cs[64 * 72];   // C rows [i][s]; reused as M [i][j]
    __shared__ short Bs[64 * 72];   // B rows [j][s]
    __shared__ short Xt[64 * 72];   // X^T   [d][c]
    __shared__ float Acs[64];
    int tid = threadIdx.x;
    if (tid < 64) {
        float a = Aarr[(size_t)(t0l + tid) * 24 + h] * (1.f - alp);
        for (int off = 1; off < 64; off <<= 1) {
            float u = __shfl_up(a, off, 64);
            if (tid >= off) a += u;
        }
        Acs[tid] = a;
    }
    int s = tid & 63, cg = tid >> 6;
    for (int it = 0; it < 16; ++it) {
        int c = cg + (it << 2);
        int t = t0l + c;
        const bf16* bp = xp + (size_t)t * NPROJ + h * 129;
        Bs[c * 72 + s] = f2bs(bf2f(bp[1 + s]) * invB[t * 24 + h]);
        Cs[c * 72 + s] = f2bs(bf2f(bp[65 + s]) * invC[t * 24 + h]);
        Xt[s * 72 + c] = *(const short*)&xc[(size_t)t * DINNER + h * 64 + s];
    }
    __syncthreads();
    int w = tid >> 6, lane = tid & 63;
    int r16 = lane & 15, kq = (lane >> 4) << 3;
    int strip = w << 4;
    f4v acc[4];
#pragma unroll
    for (int jt = 0; jt < 4; ++jt) acc[jt] = (f4v){0.f, 0.f, 0.f, 0.f};
#pragma unroll
    for (int ks = 0; ks < 2; ++ks) {
        bf8v af = *(const bf8v*)&Cs[(strip + r16) * 72 + ks * 32 + kq];
#pragma unroll
        for (int jt = 0; jt < 4; ++jt) {
            bf8v bf_ = *(const bf8v*)&Bs[((jt << 4) + r16) * 72 + ks * 32 + kq];
            acc[jt] = __builtin_amdgcn_mfma_f32_16x16x32_bf16(af, bf_, acc[jt], 0, 0, 0);
        }
    }
    __syncthreads();
    short* Ms = Cs;
    int ibase = strip + ((lane >> 4) << 2);
#pragma unroll
    for (int jt = 0; jt < 4; ++jt) {
        int j = (jt << 4) + r16;
        float aj = Acs[j];
#pragma unroll
        for (int r = 0; r < 4; ++r) {
            int i = ibase + r;
            float m = (j <= i) ? expf(Acs[i] - aj) * acc[jt][r] : 0.f;
            Ms[i * 72 + j] = f2bs(m);
        }
    }
    __syncthreads();
    f4v accy[4];
#pragma unroll
    for (int dt = 0; dt < 4; ++dt) accy[dt] = (f4v){0.f, 0.f, 0.f, 0.f};
#pragma unroll
    for (int ks = 0; ks < 2; ++ks) {
        bf8v af = *(const bf8v*)&Ms[(strip + r16) * 72 + ks * 32 + kq];
#pragma unroll
        for (int dt = 0; dt < 4; ++dt) {
            bf8v xf = *(const bf8v*)&Xt[((dt << 4) + r16) * 72 + ks * 32 + kq];
            accy[dt] = __builtin_amdgcn_mfma_f32_16x16x32_bf16(af, xf, accy[dt], 0, 0, 0);
        }
    }
#pragma unroll
    for (int dt = 0; dt < 4; ++dt) {
        int d = (dt << 4) + r16;
#pragma unroll
        for (int r = 0; r < 4; ++r) {
            int i = ibase + r;
            ybuf[(size_t)(t0l + i) * DINNER + h * 64 + d] = f2bf(accy[dt][r]);
        }
    }
}

// ---------------------------------------------------------------- h_chunk_final + decay_chunk via MFMA
__global__ __launch_bounds__(256) void k_hchunk(const bf16* __restrict__ xp,
                                                const bf16* __restrict__ xc,
                                                const float* __restrict__ invB,
                                                const float* __restrict__ Aarr,
                                                const float* __restrict__ alpha,
                                                bf16* __restrict__ hf,
                                                float* __restrict__ dchunk,
                                                int b, int l0) {
    int g = blockIdx.x;
    int h = g >> 6, nl = g & 63;
    int t0l = nl * 64;
    size_t gidx = (size_t)(b * 24 + h) * 128 + (l0 >> 6) + nl;
    float alp = alpha[gidx];
    __shared__ short Ws[64 * 72];
    __shared__ short Xt[64 * 72];
    __shared__ float dte[64];
    int tid = threadIdx.x;
    if (tid < 64) {
        float a = Aarr[(size_t)(t0l + tid) * 24 + h] * (1.f - alp);
        for (int off = 1; off < 64; off <<= 1) {
            float u = __shfl_up(a, off, 64);
            if (tid >= off) a += u;
        }
        float total = __shfl(a, 63, 64);
        dte[tid] = expf(total - a);
        if (tid == 0) dchunk[gidx] = expf(total);
    }
    __syncthreads();
    int s = tid & 63, cg = tid >> 6;
    for (int it = 0; it < 16; ++it) {
        int c = cg + (it << 2);
        int t = t0l + c;
        Ws[s * 72 + c] = f2bs(bf2f(xp[(size_t)t * NPROJ + h * 129 + 1 + s]) * invB[t * 24 + h] * dte[c]);
        Xt[s * 72 + c] = *(const short*)&xc[(size_t)t * DINNER + h * 64 + s];
    }
    __syncthreads();
    int w = tid >> 6, lane = tid & 63;
    int r16 = lane & 15, kq = (lane >> 4) << 3;
    int strip = w << 4;
    f4v acc[4];
#pragma unroll
    for (int dt = 0; dt < 4; ++dt) acc[dt] = (f4v){0.f, 0.f, 0.f, 0.f};
#pragma unroll
    for (int ks = 0; ks < 2; ++ks) {
        bf8v af = *(const bf8v*)&Ws[(strip + r16) * 72 + ks * 32 + kq];
#pragma unroll
        for (int dt = 0; dt < 4; ++dt) {
            bf8v xf = *(const bf8v*)&Xt[((dt << 4) + r16) * 72 + ks * 32 + kq];
            acc[dt] = __builtin_amdgcn_mfma_f32_16x16x32_bf16(af, xf, acc[dt], 0, 0, 0);
        }
    }
    size_t hbase = (size_t)(h * SEG_CH + nl) * 4096;
    int sbase = strip + ((lane >> 4) << 2);
#pragma unroll
    for (int dt = 0; dt < 4; ++dt) {
        int d = (dt << 4) + r16;
#pragma unroll
        for (int r = 0; r < 4; ++r)
            hf[hbase + (size_t)(sbase + r) * 64 + d] = f2bf(acc[dt][r]);
    }
}

// ---------------------------------------------------------------- chunk scan (prefetched)
__global__ __launch_bounds__(256) void k_scan(bf16* __restrict__ hf,
                                              const float* __restrict__ dchunk,
                                              float* __restrict__ carry,
                                              int b, int l0) {
    int h = blockIdx.x >> 4;
    int e = ((blockIdx.x & 15) << 8) + threadIdx.x;
    int bh = b * 24 + h;
    float c = (l0 == 0) ? 0.f : carry[(size_t)bh * 4096 + e];
    size_t a = (size_t)h * SEG_CH * 4096 + e;
    float v = bf2f(hf[a]);
    const float* dcp = dchunk + (size_t)bh * 128 + (l0 >> 6);
    for (int nl = 0; nl < SEG_CH; ++nl) {
        float dc = dcp[nl];
        float vn = (nl + 1 < SEG_CH) ? bf2f(hf[a + 4096]) : 0.f;
        hf[a] = f2bf(c);
        c = dc * c + v;
        v = vn;
        a += 4096;
    }
    carry[(size_t)bh * 4096 + e] = c;
}

// ---------------------------------------------------------------- Y_inter + gate via MFMA (in place on ybuf)
__global__ __launch_bounds__(256) void k_inter(const bf16* __restrict__ xp,
                                               const float* __restrict__ invC,
                                               const float* __restrict__ Aarr,
                                               const float* __restrict__ alpha,
                                               const bf16* __restrict__ hf,
                                               const bf16* __restrict__ zbuf,
                                               bf16* __restrict__ ybuf,
                                               int b, int l0) {
    int g = blockIdx.x;
    int h = g >> 6, nl = g & 63;
    int t0l = nl * 64;
    float alp = alpha[(size_t)(b * 24 + h) * 128 + (l0 >> 6) + nl];
    __shared__ short Cs[64 * 72];
    __shared__ short Ht[64 * 72];
    __shared__ float dfs[64];
    int tid = threadIdx.x;
    if (tid < 64) {
        float a = Aarr[(size_t)(t0l + tid) * 24 + h] * (1.f - alp);
        for (int off = 1; off < 64; off <<= 1) {
            float u = __shfl_up(a, off, 64);
            if (tid >= off) a += u;
        }
        dfs[tid] = expf(a);
    }
    int s = tid & 63, cg = tid >> 6;
    size_t hbase = (size_t)(h * SEG_CH + nl) * 4096;
    for (int it = 0; it < 16; ++it) {
        int c = cg + (it << 2);
        int t = t0l + c;
        Cs[c * 72 + s] = f2bs(bf2f(xp[(size_t)t * NPROJ + h * 129 + 65 + s]) * invC[t * 24 + h]);
        Ht[s * 72 + c] = *(const short*)&hf[hbase + (size_t)c * 64 + s];
    }
    __syncthreads();
    int w = tid >> 6, lane = tid & 63;
    int r16 = lane & 15, kq = (lane >> 4) << 3;
    int strip = w << 4;
    f4v acc[4];
#pragma unroll
    for (int dt = 0; dt < 4; ++dt) acc[dt] = (f4v){0.f, 0.f, 0.f, 0.f};
#pragma unroll
    for (int ks = 0; ks < 2; ++ks) {
        bf8v af = *(const bf8v*)&Cs[(strip + r16) * 72 + ks * 32 + kq];
#pragma unroll
        for (int dt = 0; dt < 4; ++dt) {
            bf8v hfr = *(const bf8v*)&Ht[((dt << 4) + r16) * 72 + ks * 32 + kq];
            acc[dt] = __builtin_amdgcn_mfma_f32_16x16x32_bf16(af, hfr, acc[dt], 0, 0, 0);
        }
    }
    int ibase = strip + ((lane >> 4) << 2);
#pragma unroll
    for (int dt = 0; dt < 4; ++dt) {
        int d = (dt << 4) + r16;
#pragma unroll
        for (int r = 0; r < 4; ++r) {
            int i = ibase + r;
            float df = dfs[i];
            size_t yoff = (size_t)(t0l + i) * DINNER + h * 64 + d;
            float Y = clampf(bf2f(ybuf[yoff]) + df * acc[dt][r], -100.f, 100.f);
            float zz = bf2f(zbuf[yoff]);
            ybuf[yoff] = f2bf(Y / (1.f + expf(-zz)));
        }
    }
}

// ---------------------------------------------------------------- launch
extern "C" void kernel_launch(void* const* d_in, const int* in_sizes, int n_in,
                              void* d_out, int out_size, void* d_ws, size_t ws_size,
                              hipStream_t stream) {
    const float* hs     = (const float*)d_in[0];
    const float* norm_w = (const float*)d_in[1];
    const float* w1     = (const float*)d_in[2];
    const float* b1     = (const float*)d_in[3];
    const float* cw     = (const float*)d_in[4];
    const float* cbias  = (const float*)d_in[5];
    const float* w2     = (const float*)d_in[6];
    const float* b2     = (const float*)d_in[7];
    const float* A_log  = (const float*)d_in[8];
    const float* l2ab   = (const float*)d_in[9];
    const float* l2b    = (const float*)d_in[10];
    const float* ema0   = (const float*)d_in[11];
    const float* w3     = (const float*)d_in[12];
    const float* b3     = (const float*)d_in[13];
    const float* rg     = (const float*)d_in[14];
    float* out = (float*)d_out;

    const bool BIG = ws_size >= (size_t)172 * 1024 * 1024;

    char* base = (char*)d_ws;
    size_t off = 0;
    auto alloc = [&](size_t bytes) -> void* {
        void* p = base + off;
        off += (bytes + 255) & ~(size_t)255;
        return p;
    };
    bf16* w1bf  = (bf16*)alloc((size_t)2 * DINNER * DMODEL * 2);
    bf16* w2bf  = (bf16*)alloc((size_t)NPROJP * DINNER * 2);   // padded to 3200 rows
    bf16* w3bf  = (bf16*)alloc((size_t)DMODEL * DINNER * 2);
    bf16* xn    = (bf16*)alloc((size_t)SEG_T * DMODEL * 2);
    bf16* zbuf  = (bf16*)alloc((size_t)SEG_T * DINNER * 2);
    bf16* ybuf  = (bf16*)alloc((size_t)SEG_T * DINNER * 2);
    bf16* hf    = (bf16*)alloc((size_t)NHEADS * SEG_CH * 4096 * 2);
    bf16* xhalo = (bf16*)alloc((size_t)2 * 3 * DINNER * 2);
    float* cs   = (float*)alloc((size_t)6144 * 4);
    float* alp  = (float*)alloc((size_t)6144 * 4);
    float* dch  = (float*)alloc((size_t)6144 * 4);
    float* carry= (float*)alloc((size_t)48 * 4096 * 4);
    size_t ntokA = BIG ? (size_t)NTOK : (size_t)SEG_T;
    bf16* xp    = (bf16*)alloc(ntokA * NPROJ * 2);
    float* Aarr = (float*)alloc(ntokA * 24 * 4);
    float* invB = (float*)alloc(ntokA * 24 * 4);
    float* invC = (float*)alloc(ntokA * 24 * 4);
    bf16* xbuf  = ybuf;
    bf16* xc_all = (bf16*)d_out;

    {
        int n1 = 2 * DINNER * DMODEL / 4, n2 = NPROJ * DINNER / 4, n3 = DMODEL * DINNER / 4;
        k_cvt<<<(n1 + 255) / 256, 256, 0, stream>>>(w1, w1bf, n1);
        k_cvt<<<(n2 + 255) / 256, 256, 0, stream>>>(w2, w2bf, n2);
        k_cvt<<<(n3 + 255) / 256, 256, 0, stream>>>(w3, w3bf, n3);
        int nz = (NPROJP - NPROJ) * DINNER;
        k_zero<<<(nz + 255) / 256, 256, 0, stream>>>(w2bf + (size_t)NPROJ * DINNER, nz);
    }

    const dim3 gX(DINNER / 128, SEG_T / 128);            // 12 x 32
    const dim3 gP(NPROJP / 128, SEG_T / 128);            // 25 x 32
    const dim3 gPall(NPROJP / 128, NTOK / 128);          // 25 x 128
    const dim3 gO(DMODEL / 128, SEG_T / 128);            // 6 x 32

    // ---------------- phase 1: front-end for all tokens; xc cached into d_out
    for (int s = 0; s < NSEG; ++s) {
        size_t t0 = (size_t)s * SEG_T;
        int l0 = (int)(t0 & (L_SEQ - 1));
        const float* hseg = hs + t0 * DMODEL;
        bf16* xc = xc_all + t0 * DINNER;
        k_rmsnorm<<<SEG_T, 256, 0, stream>>>(hseg, norm_w, xn);
        k_mgemm<bf16, 0><<<gX, 256, 0, stream>>>(xn, w1bf, b1, xbuf,
                                                 SEG_T, DINNER, DMODEL, nullptr, nullptr);
        k_save_halo<<<18, 256, 0, stream>>>(xbuf, xhalo + (size_t)((s + 1) & 1) * 3 * DINNER);
        k_conv_silu<<<dim3(DINNER / 256, SEG_T), 256, 0, stream>>>(
            xbuf, xhalo + (size_t)(s & 1) * 3 * DINNER, cw, cbias, xc, l0);
        if (!BIG) {
            int b = (int)(t0 >> 13);
            k_mgemm<bf16, 0><<<gP, 256, 0, stream>>>(xc, w2bf, b2, xp,
                                                     SEG_T, NPROJ, DINNER, nullptr, nullptr);
            k_prep<<<SEG_T * 24 / 4, 256, 0, stream>>>(xp, A_log, Aarr, invB, invC);
            k_surprise<<<NHEADS * SEG_CH, 256, 0, stream>>>(xp, xc, invB, cs, b, l0);
        }
    }
    if (BIG) {
        k_mgemm<bf16, 0><<<gPall, 256, 0, stream>>>(xc_all, w2bf, b2, xp,
                                                    NTOK, NPROJ, DINNER, nullptr, nullptr);
        k_prep<<<NTOK * 24 / 4, 256, 0, stream>>>(xp, A_log, Aarr, invB, invC);
        k_surprise_all<<<6144, 256, 0, stream>>>(xp, xc_all, invB, cs);
    }
    k_alpha<<<24, 256, 0, stream>>>(cs, ema0, l2ab, l2b, alp);

    // ---------------- phase 2: SSM + output per segment
    for (int s = 0; s < NSEG; ++s) {
        size_t t0 = (size_t)s * SEG_T;
        int l0 = (int)(t0 & (L_SEQ - 1));
        int b  = (int)(t0 >> 13);
        const float* hseg = hs + t0 * DMODEL;
        bf16* xc = xc_all + t0 * DINNER;
        const bf16* xpS;
        const float* AarrS;
        const float* invBS;
        const float* invCS;
        k_rmsnorm<<<SEG_T, 256, 0, stream>>>(hseg, norm_w, xn);
        k_mgemm<bf16, 0><<<gX, 256, 0, stream>>>(xn, w1bf + (size_t)DINNER * DMODEL,
                                                 b1 + DINNER, zbuf,
                                                 SEG_T, DINNER, DMODEL, nullptr, nullptr);
        if (BIG) {
            xpS   = xp   + t0 * NPROJ;
            AarrS = Aarr + t0 * 24;
            invBS = invB + t0 * 24;
            invCS = invC + t0 * 24;
        } else {
            k_mgemm<bf16, 0><<<gP, 256, 0, stream>>>(xc, w2bf, b2, xp,
                                                     SEG_T, NPROJ, DINNER, nullptr, nullptr);
            k_prep<<<SEG_T * 24 / 4, 256, 0, stream>>>(xp, A_log, Aarr, invB, invC);
            xpS = xp; AarrS = Aarr; invBS = invB; invCS = invC;
        }
        k_intra<<<NHEADS * SEG_CH, 256, 0, stream>>>(xpS, xc, invBS, invCS, AarrS, alp, ybuf, b, l0);
        k_hchunk<<<NHEADS * SEG_CH, 256, 0, stream>>>(xpS, xc, invBS, AarrS, alp, hf, dch, b, l0);
        k_scan<<<384, 256, 0, stream>>>(hf, dch, carry, b, l0);
        k_inter<<<NHEADS * SEG_CH, 256, 0, stream>>>(xpS, invCS, AarrS, alp, hf, zbuf, ybuf, b, l0);
        k_mgemm<float, 1><<<gO, 256, 0, stream>>>(ybuf, w3bf, b3, out + t0 * DMODEL,
                                                  SEG_T, DMODEL, DINNER, hseg, rg);
    }
}